// Round 3
// baseline (880.657 us; speedup 1.0000x reference)
//
#include <hip/hip_runtime.h>
#include <cstdio>

#define E_DIM 512
#define L_DIM 4096
#define B_DIM 8
#define H_DIM 8
#define T_DIM 2
#define M_ROWS 32768

typedef __attribute__((ext_vector_type(8))) __bf16 bf16x8;
typedef __attribute__((ext_vector_type(4))) float f32x4;

static __device__ __forceinline__ unsigned short f2bf(float f) {
  unsigned int u = __float_as_uint(f);
  return (unsigned short)((u + 0x7FFFu + ((u >> 16) & 1u)) >> 16);
}
static __device__ __forceinline__ unsigned int pkbf(float lo, float hi) {
  return (unsigned int)f2bf(lo) | ((unsigned int)f2bf(hi) << 16);
}
static __device__ __forceinline__ float bf2f(unsigned short u) {
  return __uint_as_float((unsigned int)u << 16);
}
static __device__ __forceinline__ void unpk8(uint4 u, float* f) {
  f[0] = bf2f((unsigned short)u.x); f[1] = bf2f((unsigned short)(u.x >> 16));
  f[2] = bf2f((unsigned short)u.y); f[3] = bf2f((unsigned short)(u.y >> 16));
  f[4] = bf2f((unsigned short)u.z); f[5] = bf2f((unsigned short)(u.z >> 16));
  f[6] = bf2f((unsigned short)u.w); f[7] = bf2f((unsigned short)(u.w >> 16));
}
// XOR swizzle at 8-elem (16B) granules, 64-elem and 128-elem rows
static __device__ __forceinline__ int swz64(int row, int e) {
  return row * 64 + ((((e >> 3) ^ row) & 7) << 3) + (e & 7);
}
static __device__ __forceinline__ int swz128(int row, int e) {
  return row * 128 + ((((e >> 3) ^ row) & 7) << 3) + ((e >> 3) & 8) * 8 + (e & 7);
}
// NOTE: swz128 must keep granule bit3 (e>=64 half) intact: granule g=e>>3 in 0..15,
// g' = (g & 8) | ((g ^ row) & 7). Implemented above: ((e>>3)&8)*8 adds back the
// high-granule offset (8 granules * 8 elems = 64).

// ---------------------------------------------------------------------------
__global__ void sincos_kernel(float* __restrict__ sintab, float* __restrict__ costab) {
  int i = blockIdx.x * blockDim.x + threadIdx.x;
  if (i < L_DIM) {
    float idx = 1.57079632679489662f * (float)(i + 1) / (float)L_DIM;
    sintab[i] = sinf(idx);
    costab[i] = cosf(idx);
  }
}

// fp32 -> bf16 bulk conversion (n8 = count/8)
__global__ void convf2b(const float* __restrict__ src, unsigned short* __restrict__ dst,
                        int n8) {
  for (int i = blockIdx.x * blockDim.x + threadIdx.x; i < n8; i += gridDim.x * blockDim.x) {
    float4 a = *(const float4*)(src + (size_t)i * 8);
    float4 b = *(const float4*)(src + (size_t)i * 8 + 4);
    uint4 o;
    o.x = pkbf(a.x, a.y); o.y = pkbf(a.z, a.w);
    o.z = pkbf(b.x, b.y); o.w = pkbf(b.z, b.w);
    *(uint4*)(dst + (size_t)i * 8) = o;
  }
}

// ---------------------------------------------------------------------------
// Y[M][512] = X[M][512] @ W[512][512]^T + bias; bf16 in, bf16 or fp32 out
// ---------------------------------------------------------------------------
template <bool OUTF32>
__global__ __launch_bounds__(256) void gemm_bf16(
    const unsigned short* __restrict__ X, const unsigned short* __restrict__ W,
    const float* __restrict__ bias, void* __restrict__ Yv) {
  __shared__ __align__(16) unsigned short As[128 * 64];
  __shared__ __align__(16) unsigned short Bs[128 * 64];
  const int tid = threadIdx.x;
  const int m0 = blockIdx.x * 128;
  const int n0 = blockIdx.y * 128;
  const int lane = tid & 63;
  const int w = tid >> 6;
  const int wr = w >> 1, wc = w & 1;
  const int lr = lane & 15;
  const int lk = (lane >> 4) * 8;
  f32x4 acc[4][4];
#pragma unroll
  for (int i = 0; i < 4; ++i)
#pragma unroll
    for (int j = 0; j < 4; ++j) acc[i][j] = (f32x4){0.f, 0.f, 0.f, 0.f};

  for (int k0 = 0; k0 < 512; k0 += 64) {
    uint4 va[4], vb[4];
#pragma unroll
    for (int i = 0; i < 4; ++i) {
      int gi = tid + i * 256;  // granule id 0..1023
      int r = gi >> 3;
      int g = gi & 7;
      va[i] = *(const uint4*)(X + (size_t)(m0 + r) * 512 + k0 + g * 8);
      vb[i] = *(const uint4*)(W + (size_t)(n0 + r) * 512 + k0 + g * 8);
    }
    __syncthreads();
#pragma unroll
    for (int i = 0; i < 4; ++i) {
      int gi = tid + i * 256;
      int r = gi >> 3;
      int g = gi & 7;
      int off = r * 64 + ((g ^ (r & 7)) << 3);
      *(uint4*)&As[off] = va[i];
      *(uint4*)&Bs[off] = vb[i];
    }
    __syncthreads();
#pragma unroll
    for (int kk = 0; kk < 2; ++kk) {
      bf16x8 av[4], bv[4];
      int ke = kk * 32 + lk;
#pragma unroll
      for (int fm = 0; fm < 4; ++fm)
        av[fm] = *(const bf16x8*)&As[swz64(wr * 64 + fm * 16 + lr, ke)];
#pragma unroll
      for (int fn = 0; fn < 4; ++fn)
        bv[fn] = *(const bf16x8*)&Bs[swz64(wc * 64 + fn * 16 + lr, ke)];
#pragma unroll
      for (int fm = 0; fm < 4; ++fm)
#pragma unroll
        for (int fn = 0; fn < 4; ++fn)
          acc[fm][fn] = __builtin_amdgcn_mfma_f32_16x16x32_bf16(av[fm], bv[fn],
                                                                acc[fm][fn], 0, 0, 0);
    }
  }
  const int rq = lane >> 4;
#pragma unroll
  for (int fn = 0; fn < 4; ++fn) {
    int col = n0 + wc * 64 + fn * 16 + lr;
    float bb = bias[col];
#pragma unroll
    for (int fm = 0; fm < 4; ++fm) {
      int rbase = m0 + wr * 64 + fm * 16 + rq * 4;
#pragma unroll
      for (int j = 0; j < 4; ++j) {
        float v = acc[fm][fn][j] + bb;
        if (OUTF32)
          ((float*)Yv)[(size_t)(rbase + j) * 512 + col] = v;
        else
          ((unsigned short*)Yv)[(size_t)(rbase + j) * 512 + col] = f2bf(v);
      }
    }
  }
}

// ---------------------------------------------------------------------------
// k softmax column stats on bf16 proj (partials over 128-row s-chunks)
// ---------------------------------------------------------------------------
__global__ __launch_bounds__(256) void kcolstats_part(
    const unsigned short* __restrict__ Kp, float* __restrict__ pmax,
    float* __restrict__ psum) {
  int b = blockIdx.y;
  int chunk = blockIdx.z;
  int tx = threadIdx.x;
  int f = blockIdx.x * 64 + tx;
  int sy = threadIdx.y;
  const unsigned short* p = Kp + ((size_t)b * L_DIM + chunk * 128) * 512 + f;
  float m = -3.0e38f, sum = 0.f;
  for (int s = sy; s < 128; s += 4) {
    float v = bf2f(p[(size_t)s * 512]);
    float nm = fmaxf(m, v);
    sum = sum * __expf(m - nm) + __expf(v - nm);
    m = nm;
  }
  __shared__ float sm[4][64];
  __shared__ float ss[4][64];
  sm[sy][tx] = m;
  ss[sy][tx] = sum;
  __syncthreads();
  if (sy == 0) {
    float M = sm[0][tx];
    float S = ss[0][tx];
#pragma unroll
    for (int i = 1; i < 4; ++i) {
      float mi = sm[i][tx];
      float nm = fmaxf(M, mi);
      S = S * __expf(M - nm) + ss[i][tx] * __expf(mi - nm);
      M = nm;
    }
    pmax[(size_t)chunk * 4096 + b * E_DIM + f] = M;
    psum[(size_t)chunk * 4096 + b * E_DIM + f] = S;
  }
}

__global__ void kcolstats_reduce(const float* __restrict__ pmax,
                                 const float* __restrict__ psum,
                                 float* __restrict__ colmax,
                                 float* __restrict__ colinv) {
  int i = blockIdx.x * 256 + threadIdx.x;
  float M = -3.0e38f, S = 0.f;
#pragma unroll
  for (int c = 0; c < 32; ++c) {
    float m = pmax[(size_t)c * 4096 + i];
    float s = psum[(size_t)c * 4096 + i];
    float nm = fmaxf(M, m);
    S = S * __expf(M - nm) + s * __expf(m - nm);
    M = nm;
  }
  colmax[i] = M;
  colinv[i] = 1.f / S;
}

// ---------------------------------------------------------------------------
// kv partials via MFMA: C[d 0..63][ncol 0..127] = sum_s k2[s][d]*B[s][ncol]
// B = [v*sin | v*cos]. A,B staged transposed ([x][s]) in swizzled LDS.
// grid (8 s-chunks, 64 n), 256 thr (4 waves).
// ---------------------------------------------------------------------------
__global__ __launch_bounds__(256) void kv_mfma(
    const unsigned short* __restrict__ Kp, const float* __restrict__ Vp,
    const float* __restrict__ colmax, const float* __restrict__ colinv,
    const float* __restrict__ sintab, const float* __restrict__ costab,
    float* __restrict__ kvpart) {
  __shared__ __align__(16) unsigned short kT[64 * 64];    // [d][s]
  __shared__ __align__(16) unsigned short vT[128 * 64];   // [ncol][s]
  __shared__ float cmaxs[64], cinvs[64];
  const int tid = threadIdx.x;
  const int chunk = blockIdx.x;
  const int n = blockIdx.y;
  const int b = n >> 3, h = n & 7;
  if (tid < 64) {
    cmaxs[tid] = colmax[b * E_DIM + h * 64 + tid];
    cinvs[tid] = colinv[b * E_DIM + h * 64 + tid];
  }
  const int lane = tid & 63;
  const int w = tid >> 6;
  const int lr = lane & 15;
  const int lk = (lane >> 4) * 8;
  const int sp = tid & 31;   // s-pair index
  const int g = tid >> 5;    // 8-elem group (d or m)
  f32x4 acc[4][2];
#pragma unroll
  for (int i = 0; i < 4; ++i) {
    acc[i][0] = (f32x4){0.f, 0.f, 0.f, 0.f};
    acc[i][1] = (f32x4){0.f, 0.f, 0.f, 0.f};
  }
  __syncthreads();  // cmaxs ready

  for (int st = 0; st < 8; ++st) {
    int sA = chunk * 512 + st * 64 + 2 * sp;  // even
    // K: rows sA, sA+1, cols h*64 + g*8..+8 (bf16)
    const unsigned short* kp = Kp + ((size_t)b * L_DIM + sA) * 512 + h * 64 + g * 8;
    uint4 ka = *(const uint4*)kp;
    uint4 kb = *(const uint4*)(kp + 512);
    // V (fp32, torch-faithful row permutation; sA,sA+1 share the 512-block)
    int vr = ((sA >> 9) << 12) + ((sA & 511) << 3) + b;
    const float* vp = Vp + (size_t)vr * 512 + h * 64 + g * 8;
    float4 v0a = *(const float4*)vp;
    float4 v0b = *(const float4*)(vp + 4);
    float4 v1a = *(const float4*)(vp + 8 * 512);
    float4 v1b = *(const float4*)(vp + 8 * 512 + 4);
    float kfa[8], kfb[8];
    unpk8(ka, kfa);
    unpk8(kb, kfb);
    float vA[8], vB[8];
    *(float4*)&vA[0] = v0a; *(float4*)&vA[4] = v0b;
    *(float4*)&vB[0] = v1a; *(float4*)&vB[4] = v1b;
    float sS = sintab[sA], sC = costab[sA];
    float tS = sintab[sA + 1], tC = costab[sA + 1];
    __syncthreads();  // previous iteration's MFMA LDS reads done
#pragma unroll
    for (int i = 0; i < 8; ++i) {
      int d = g * 8 + i;
      float e0 = __expf(kfa[i] - cmaxs[d]) * cinvs[d];
      float e1 = __expf(kfb[i] - cmaxs[d]) * cinvs[d];
      *(unsigned int*)&kT[swz64(d, 2 * sp)] = pkbf(e0, e1);
    }
#pragma unroll
    for (int i = 0; i < 8; ++i) {
      int m = g * 8 + i;
      *(unsigned int*)&vT[swz64(m, 2 * sp)] = pkbf(vA[i] * sS, vB[i] * tS);
      *(unsigned int*)&vT[swz64(64 + m, 2 * sp)] = pkbf(vA[i] * sC, vB[i] * tC);
    }
    __syncthreads();
#pragma unroll
    for (int kk = 0; kk < 2; ++kk) {
      int ke = kk * 32 + lk;
      bf16x8 av[4], bv[2];
#pragma unroll
      for (int fm = 0; fm < 4; ++fm)
        av[fm] = *(const bf16x8*)&kT[swz64(fm * 16 + lr, ke)];
#pragma unroll
      for (int fn = 0; fn < 2; ++fn)
        bv[fn] = *(const bf16x8*)&vT[swz64(w * 32 + fn * 16 + lr, ke)];
#pragma unroll
      for (int fm = 0; fm < 4; ++fm)
#pragma unroll
        for (int fn = 0; fn < 2; ++fn)
          acc[fm][fn] = __builtin_amdgcn_mfma_f32_16x16x32_bf16(av[fm], bv[fn],
                                                                acc[fm][fn], 0, 0, 0);
    }
  }
  const int rq = lane >> 4;
#pragma unroll
  for (int fn = 0; fn < 2; ++fn) {
    int ncol = w * 32 + fn * 16 + lr;
    int m = ncol & 63;
    int ddbase = (ncol >> 6) * 64;
#pragma unroll
    for (int fm = 0; fm < 4; ++fm) {
#pragma unroll
      for (int j = 0; j < 4; ++j) {
        int dd = ddbase + fm * 16 + rq * 4 + j;
        kvpart[(((size_t)chunk * 64 + n) * 64 + m) * 128 + dd] = acc[fm][fn][j];
      }
    }
  }
}

// reduce 8 chunks -> kvT bf16, PRE-SWIZZLED [n][m][dd] for the out kernel
__global__ void kv_reduce_swz(const float* __restrict__ part,
                              unsigned short* __restrict__ kvT) {
  int i = blockIdx.x * 256 + threadIdx.x;  // (n*64+m)*128+dd
  float s = 0.f;
#pragma unroll
  for (int c = 0; c < 8; ++c) s += part[(size_t)c * 524288 + i];
  int dd = i & 127;
  int m = (i >> 7) & 63;
  int nm = i >> 7;
  int gg = dd >> 3;
  int e = ((gg & 8) | ((gg ^ m) & 7)) * 8 + (dd & 7);
  kvT[(size_t)nm * 128 + e] = f2bf(s);
}

// ---------------------------------------------------------------------------
// out2[l][m] (+)= sum_dd q2[l][dd] * kvT[m][dd]   via MFMA, K=128
// q-softmax + sin/cos fused into A staging. kvs copied linearly (pre-swizzled).
// grid (64 l-chunks, 64 n), 256 thr (4 waves, 32x32 each).
// ---------------------------------------------------------------------------
template <bool ACCUM>
__global__ __launch_bounds__(256) void out_mfma(
    const unsigned short* __restrict__ Qp, const unsigned short* __restrict__ kvT,
    const float* __restrict__ sintab, const float* __restrict__ costab,
    float* __restrict__ out2) {
  __shared__ __align__(16) unsigned short q2s[64 * 128];
  __shared__ __align__(16) unsigned short kvs[64 * 128];
  const int tid = threadIdx.x;
  const int lc = blockIdx.x;
  const int n = blockIdx.y;
  const int b = n >> 3, h = n & 7;
  const int lane = tid & 63;
  const int w = tid >> 6;
  const uint4* src = (const uint4*)(kvT + (size_t)n * 8192);
  uint4* dstl = (uint4*)kvs;
#pragma unroll
  for (int i = 0; i < 4; ++i) dstl[tid + i * 256] = src[tid + i * 256];
  const int l0 = lc * 64;
#pragma unroll 1
  for (int i = 0; i < 16; ++i) {
    int l = i * 4 + w;
    float x = bf2f(Qp[((size_t)b * L_DIM + l0 + l) * 512 + h * 64 + lane]);
    float m = x;
#pragma unroll
    for (int off = 32; off > 0; off >>= 1) m = fmaxf(m, __shfl_xor(m, off));
    float e = __expf(x - m);
    float ssum = e;
#pragma unroll
    for (int off = 32; off > 0; off >>= 1) ssum += __shfl_xor(ssum, off);
    float p = e / ssum;
    int gl = l0 + l;
    q2s[swz128(l, lane)] = f2bf(p * sintab[gl]);
    q2s[swz128(l, 64 + lane)] = f2bf(p * costab[gl]);
  }
  __syncthreads();
  const int wr = w >> 1, wc = w & 1;
  const int lr = lane & 15;
  const int lk = (lane >> 4) * 8;
  f32x4 acc[2][2];
  acc[0][0] = acc[0][1] = acc[1][0] = acc[1][1] = (f32x4){0.f, 0.f, 0.f, 0.f};
#pragma unroll
  for (int ks = 0; ks < 4; ++ks) {
    int ke = ks * 32 + lk;
    bf16x8 av[2], bv[2];
#pragma unroll
    for (int fm = 0; fm < 2; ++fm)
      av[fm] = *(const bf16x8*)&q2s[swz128(wr * 32 + fm * 16 + lr, ke)];
#pragma unroll
    for (int fn = 0; fn < 2; ++fn)
      bv[fn] = *(const bf16x8*)&kvs[swz128(wc * 32 + fn * 16 + lr, ke)];
#pragma unroll
    for (int fm = 0; fm < 2; ++fm)
#pragma unroll
      for (int fn = 0; fn < 2; ++fn)
        acc[fm][fn] = __builtin_amdgcn_mfma_f32_16x16x32_bf16(av[fm], bv[fn],
                                                              acc[fm][fn], 0, 0, 0);
  }
  const int rq = lane >> 4;
#pragma unroll
  for (int fn = 0; fn < 2; ++fn) {
    int col = h * 64 + wc * 32 + fn * 16 + lr;
#pragma unroll
    for (int fm = 0; fm < 2; ++fm) {
      int row = l0 + wr * 32 + fm * 16 + rq * 4;
#pragma unroll
      for (int j = 0; j < 4; ++j) {
        float* op = out2 + ((size_t)b * L_DIM + row + j) * 512 + col;
        if (ACCUM)
          *op += acc[fm][fn][j];
        else
          *op = acc[fm][fn][j];
      }
    }
  }
}

// ---------------------------------------------------------------------------
extern "C" void kernel_launch(void* const* d_in, const int* in_sizes, int n_in,
                              void* d_out, int out_size, void* d_ws, size_t ws_size,
                              hipStream_t stream) {
  const float* query = (const float*)d_in[0];
  const float* key   = (const float*)d_in[1];
  const float* value = (const float*)d_in[2];
  const float* Wq    = (const float*)d_in[3];
  const float* bq    = (const float*)d_in[4];
  const float* Wk    = (const float*)d_in[5];
  const float* bk    = (const float*)d_in[6];
  const float* Wv    = (const float*)d_in[7];
  const float* bv    = (const float*)d_in[8];
  const float* Wout  = (const float*)d_in[9];
  const float* bout  = (const float*)d_in[10];
  float* out = (float*)d_out;
  float* ws = (float*)d_ws;

  // workspace layout (fp32 slot units)
  const size_t F_PROJ = 0;                       // proj bf16: 16.8M u16
  const size_t F_OUT2 = F_PROJ + 8388608;        // Vp fp32, later out2 fp32
  const size_t F_KVP  = F_OUT2 + 16777216;       // kv partials fp32 (8 chunks)
  const size_t F_KVT  = F_KVP + 4194304;         // kvT bf16, 2 terms
  const size_t F_XBUF = F_KVT + 524288;          // bf16 input buffer (time-shared)
  const size_t F_WBF  = F_XBUF + 8388608;        // weights bf16
  const size_t F_CMAX = F_WBF + 786432;
  const size_t F_CINV = F_CMAX + 4096;
  const size_t F_SIN  = F_CINV + 4096;
  const size_t F_COS  = F_SIN + 4096;
  const size_t TOTALF = F_COS + 4096;
  if (ws_size < TOTALF * sizeof(float)) {
    fprintf(stderr, "kernel_launch: ws too small (%zu < %zu)\n", ws_size, TOTALF * 4);
    return;
  }
  unsigned short* proj = (unsigned short*)(ws + F_PROJ);
  float* Vp_out2 = ws + F_OUT2;
  float* kvpart = ws + F_KVP;
  unsigned short* kvT = (unsigned short*)(ws + F_KVT);
  unsigned short* xbuf = (unsigned short*)(ws + F_XBUF);
  unsigned short* wbf = (unsigned short*)(ws + F_WBF);
  float* cmax = ws + F_CMAX;
  float* cinv = ws + F_CINV;
  float* sintab = ws + F_SIN;
  float* costab = ws + F_COS;
  float* pmax = kvpart;            // aliases (disjoint lifetime)
  float* psum = kvpart + 131072;
  // bf16 weight offsets (u16 units)
  const size_t WQ_O = 0, WK_O = 524288, WV_O = 1048576, WOUT_O = 1310720;

  sincos_kernel<<<16, 256, 0, stream>>>(sintab, costab);
  convf2b<<<256, 256, 0, stream>>>(Wq, wbf + WQ_O, 65536);
  convf2b<<<256, 256, 0, stream>>>(Wk, wbf + WK_O, 65536);
  convf2b<<<128, 256, 0, stream>>>(Wv, wbf + WV_O, 32768);
  convf2b<<<128, 256, 0, stream>>>(Wout, wbf + WOUT_O, 32768);

  dim3 gemm_grid(M_ROWS / 128, 4);
  // V projection (fp32 out)
  convf2b<<<2048, 256, 0, stream>>>(value, xbuf, 2097152);
  gemm_bf16<true><<<gemm_grid, 256, 0, stream>>>(xbuf, wbf + WV_O, bv, Vp_out2);

  // K projections -> col softmax stats -> kv state
  convf2b<<<2048, 256, 0, stream>>>(key, xbuf, 2097152);
  for (int t = 0; t < T_DIM; ++t) {
    gemm_bf16<false><<<gemm_grid, 256, 0, stream>>>(xbuf, wbf + WK_O + t * 262144,
                                                    bk + t * 512, proj);
    kcolstats_part<<<dim3(8, 8, 32), dim3(64, 4), 0, stream>>>(proj, pmax, psum);
    kcolstats_reduce<<<16, 256, 0, stream>>>(pmax, psum, cmax, cinv);
    kv_mfma<<<dim3(8, 64), 256, 0, stream>>>(proj, Vp_out2, cmax, cinv,
                                             sintab, costab, kvpart);
    kv_reduce_swz<<<2048, 256, 0, stream>>>(kvpart, kvT + (size_t)t * 524288);
  }

  // Q projections -> output accumulation (t0 writes, t1 accumulates)
  convf2b<<<2048, 256, 0, stream>>>(query, xbuf, 2097152);
  for (int t = 0; t < T_DIM; ++t) {
    gemm_bf16<false><<<gemm_grid, 256, 0, stream>>>(xbuf, wbf + WQ_O + t * 262144,
                                                    bq + t * 512, proj);
    if (t == 0)
      out_mfma<false><<<dim3(64, 64), 256, 0, stream>>>(proj, kvT, sintab, costab,
                                                        Vp_out2);
    else
      out_mfma<true><<<dim3(64, 64), 256, 0, stream>>>(proj, kvT + 524288, sintab,
                                                       costab, Vp_out2);
  }

  // final output projection: out2 -> bf16 -> GEMM (fp32 out)
  convf2b<<<2048, 256, 0, stream>>>(Vp_out2, xbuf, 2097152);
  gemm_bf16<true><<<gemm_grid, 256, 0, stream>>>(xbuf, wbf + WOUT_O, bout, out);
}

// Round 5
// 665.730 us; speedup vs baseline: 1.3228x; 1.3228x over previous
//
#include <hip/hip_runtime.h>
#include <cstdio>

#define E_DIM 512
#define L_DIM 4096
#define B_DIM 8
#define H_DIM 8
#define T_DIM 2
#define M_ROWS 32768

typedef __attribute__((ext_vector_type(8))) __bf16 bf16x8;
typedef __attribute__((ext_vector_type(4))) float f32x4;

static __device__ __forceinline__ unsigned short f2bf(float f) {
  unsigned int u = __float_as_uint(f);
  return (unsigned short)((u + 0x7FFFu + ((u >> 16) & 1u)) >> 16);
}
static __device__ __forceinline__ unsigned int pkbf(float lo, float hi) {
  return (unsigned int)f2bf(lo) | ((unsigned int)f2bf(hi) << 16);
}
static __device__ __forceinline__ float bf2f(unsigned short u) {
  return __uint_as_float((unsigned int)u << 16);
}
static __device__ __forceinline__ void unpk8(uint4 u, float* f) {
  f[0] = bf2f((unsigned short)u.x); f[1] = bf2f((unsigned short)(u.x >> 16));
  f[2] = bf2f((unsigned short)u.y); f[3] = bf2f((unsigned short)(u.y >> 16));
  f[4] = bf2f((unsigned short)u.z); f[5] = bf2f((unsigned short)(u.z >> 16));
  f[6] = bf2f((unsigned short)u.w); f[7] = bf2f((unsigned short)(u.w >> 16));
}
// XOR swizzle at 8-elem (16B) granules
static __device__ __forceinline__ int swz64(int row, int e) {
  return row * 64 + ((((e >> 3) ^ row) & 7) << 3) + (e & 7);
}
static __device__ __forceinline__ int swz128(int row, int e) {
  return row * 128 + ((((e >> 3) ^ row) & 7) << 3) + ((e >> 3) & 8) * 8 + (e & 7);
}

// ---------------------------------------------------------------------------
__global__ void sincos_kernel(float* __restrict__ sintab, float* __restrict__ costab) {
  int i = blockIdx.x * blockDim.x + threadIdx.x;
  if (i < L_DIM) {
    float idx = 1.57079632679489662f * (float)(i + 1) / (float)L_DIM;
    sintab[i] = sinf(idx);
    costab[i] = cosf(idx);
  }
}

__global__ void convf2b(const float* __restrict__ src, unsigned short* __restrict__ dst,
                        int n8) {
  for (int i = blockIdx.x * blockDim.x + threadIdx.x; i < n8; i += gridDim.x * blockDim.x) {
    float4 a = *(const float4*)(src + (size_t)i * 8);
    float4 b = *(const float4*)(src + (size_t)i * 8 + 4);
    uint4 o;
    o.x = pkbf(a.x, a.y); o.y = pkbf(a.z, a.w);
    o.z = pkbf(b.x, b.y); o.w = pkbf(b.z, b.w);
    *(uint4*)(dst + (size_t)i * 8) = o;
  }
}

// ---------------------------------------------------------------------------
// Y[M][N] = X[M][512] @ W[N][512]^T + bias[N]; N = 512<<(NBL2-2).
// A fp32 (converted in staging) or bf16; out bf16 (split buffers at n=512
// boundary, u16 stride YHALF) or fp32. Block swizzle: id&7 -> XCD chunk of
// 32 m-panels, n fastest. LDS-staged vectorized epilogue (full-line writes).
// ---------------------------------------------------------------------------
#define YHALF 16777216
template <bool AF32, bool OUTF32, int NBL2>
__global__ __launch_bounds__(256) void gemm_xwt(
    const void* __restrict__ Xv, const unsigned short* __restrict__ W,
    const float* __restrict__ bias, void* __restrict__ Yv) {
  __shared__ __align__(16) unsigned short smem[17408];
  unsigned short* As = smem;          // 128x64
  unsigned short* Bs = smem + 8192;   // 128x64
  const int tid = threadIdx.x;
  const int id = blockIdx.x;
  const int j = id >> 3;
  const int mb = (id & 7) * 32 + (j >> NBL2);
  const int nb = j & ((1 << NBL2) - 1);
  const int m0 = mb * 128, n0 = nb * 128;
  const int lane = tid & 63;
  const int w = tid >> 6;
  const int wr = w >> 1, wc = w & 1;
  const int lr = lane & 15;
  const int lk = (lane >> 4) * 8;
  f32x4 acc[4][4];
#pragma unroll
  for (int i = 0; i < 4; ++i)
#pragma unroll
    for (int jj = 0; jj < 4; ++jj) acc[i][jj] = (f32x4){0.f, 0.f, 0.f, 0.f};

  for (int k0 = 0; k0 < 512; k0 += 64) {
    uint4 va[4], vb[4];
#pragma unroll
    for (int i = 0; i < 4; ++i) {
      int gi = tid + i * 256;
      int r = gi >> 3, g = gi & 7;
      if (AF32) {
        const float* pa = (const float*)Xv + (size_t)(m0 + r) * 512 + k0 + g * 8;
        float4 a0 = *(const float4*)pa;
        float4 a1 = *(const float4*)(pa + 4);
        uint4 o;
        o.x = pkbf(a0.x, a0.y); o.y = pkbf(a0.z, a0.w);
        o.z = pkbf(a1.x, a1.y); o.w = pkbf(a1.z, a1.w);
        va[i] = o;
      } else {
        va[i] = *(const uint4*)((const unsigned short*)Xv +
                                (size_t)(m0 + r) * 512 + k0 + g * 8);
      }
      vb[i] = *(const uint4*)(W + (size_t)(n0 + r) * 512 + k0 + g * 8);
    }
    __syncthreads();
#pragma unroll
    for (int i = 0; i < 4; ++i) {
      int gi = tid + i * 256;
      int r = gi >> 3, g = gi & 7;
      int off = r * 64 + ((g ^ (r & 7)) << 3);
      *(uint4*)&As[off] = va[i];
      *(uint4*)&Bs[off] = vb[i];
    }
    __syncthreads();
#pragma unroll
    for (int kk = 0; kk < 2; ++kk) {
      bf16x8 av[4], bv[4];
      int ke = kk * 32 + lk;
#pragma unroll
      for (int fm = 0; fm < 4; ++fm)
        av[fm] = *(const bf16x8*)&As[swz64(wr * 64 + fm * 16 + lr, ke)];
#pragma unroll
      for (int fn = 0; fn < 4; ++fn)
        bv[fn] = *(const bf16x8*)&Bs[swz64(wc * 64 + fn * 16 + lr, ke)];
#pragma unroll
      for (int fm = 0; fm < 4; ++fm)
#pragma unroll
        for (int fn = 0; fn < 4; ++fn)
          acc[fm][fn] = __builtin_amdgcn_mfma_f32_16x16x32_bf16(av[fm], bv[fn],
                                                                acc[fm][fn], 0, 0, 0);
    }
  }
  __syncthreads();  // staging reads done; smem becomes epilogue tile
  const int rq = lane >> 4;
  if (!OUTF32) {
    unsigned short* Cs = smem;  // 128 x (stride 136)
#pragma unroll
    for (int fn = 0; fn < 4; ++fn) {
      int col = wc * 64 + fn * 16 + lr;
      float bb = bias[n0 + col];
#pragma unroll
      for (int fm = 0; fm < 4; ++fm) {
        int row = wr * 64 + fm * 16 + rq * 4;
#pragma unroll
        for (int jj = 0; jj < 4; ++jj)
          Cs[(row + jj) * 136 + col] = f2bf(acc[fm][fn][jj] + bb);
      }
    }
    __syncthreads();
    unsigned short* Yb = (unsigned short*)Yv + (size_t)(n0 >> 9) * YHALF;
    const int nc = n0 & 511;
    // FIX (R4 bug): full 128x128 tile = 2048 uint4, so 8 iterations.
#pragma unroll
    for (int i = 0; i < 8; ++i) {
      int idx = tid + i * 256;     // 0..2047
      int row = idx >> 4, g = idx & 15;
      *(uint4*)(Yb + (size_t)(m0 + row) * 512 + nc + g * 8) =
          *(const uint4*)&Cs[row * 136 + g * 8];
    }
  } else {
    float* Cf = (float*)smem;  // 64 x (stride 132)
    float* Yf = (float*)Yv;
#pragma unroll
    for (int p = 0; p < 2; ++p) {
      if (p) __syncthreads();
      if (wr == p) {
#pragma unroll
        for (int fn = 0; fn < 4; ++fn) {
          int col = wc * 64 + fn * 16 + lr;
          float bb = bias[n0 + col];
#pragma unroll
          for (int fm = 0; fm < 4; ++fm) {
            int lrow = fm * 16 + rq * 4;
#pragma unroll
            for (int jj = 0; jj < 4; ++jj)
              Cf[(lrow + jj) * 132 + col] = acc[fm][fn][jj] + bb;
          }
        }
      }
      __syncthreads();
#pragma unroll
      for (int i = 0; i < 8; ++i) {
        int idx = tid + i * 256;
        int row = idx >> 5, g = idx & 31;
        *(float4*)(Yf + (size_t)(m0 + p * 64 + row) * 512 + n0 + g * 4) =
            *(const float4*)&Cf[row * 132 + g * 4];
      }
    }
  }
}

// ---------------------------------------------------------------------------
// k softmax column stats (bf16 proj), partials over 128-row s-chunks
// ---------------------------------------------------------------------------
__global__ __launch_bounds__(256) void kcolstats_part(
    const unsigned short* __restrict__ Kp, float* __restrict__ pmax,
    float* __restrict__ psum) {
  int b = blockIdx.y;
  int chunk = blockIdx.z;
  int tx = threadIdx.x;
  int f = blockIdx.x * 64 + tx;
  int sy = threadIdx.y;
  const unsigned short* p = Kp + ((size_t)b * L_DIM + chunk * 128) * 512 + f;
  float m = -3.0e38f, sum = 0.f;
  for (int s = sy; s < 128; s += 4) {
    float v = bf2f(p[(size_t)s * 512]);
    float nm = fmaxf(m, v);
    sum = sum * __expf(m - nm) + __expf(v - nm);
    m = nm;
  }
  __shared__ float sm[4][64];
  __shared__ float ss[4][64];
  sm[sy][tx] = m;
  ss[sy][tx] = sum;
  __syncthreads();
  if (sy == 0) {
    float M = sm[0][tx];
    float S = ss[0][tx];
#pragma unroll
    for (int i = 1; i < 4; ++i) {
      float mi = sm[i][tx];
      float nm = fmaxf(M, mi);
      S = S * __expf(M - nm) + ss[i][tx] * __expf(mi - nm);
      M = nm;
    }
    pmax[(size_t)chunk * 4096 + b * E_DIM + f] = M;
    psum[(size_t)chunk * 4096 + b * E_DIM + f] = S;
  }
}

__global__ void kcolstats_reduce(const float* __restrict__ pmax,
                                 const float* __restrict__ psum,
                                 float* __restrict__ colmax,
                                 float* __restrict__ colinv) {
  int i = blockIdx.x * 256 + threadIdx.x;
  float M = -3.0e38f, S = 0.f;
#pragma unroll
  for (int c = 0; c < 32; ++c) {
    float m = pmax[(size_t)c * 4096 + i];
    float s = psum[(size_t)c * 4096 + i];
    float nm = fmaxf(M, m);
    S = S * __expf(M - nm) + s * __expf(m - nm);
    M = nm;
  }
  colmax[i] = M;
  colinv[i] = 1.f / S;
}

// ---------------------------------------------------------------------------
// kv partials via MFMA: C[d][ncol] = sum_s k2[s][d]*B[s][ncol], B=[v*sin|v*cos]
// grid (8 s-chunks, 64 n), 256 thr. V bf16.
// ---------------------------------------------------------------------------
__global__ __launch_bounds__(256) void kv_mfma(
    const unsigned short* __restrict__ Kp, const unsigned short* __restrict__ Vpb,
    const float* __restrict__ colmax, const float* __restrict__ colinv,
    const float* __restrict__ sintab, const float* __restrict__ costab,
    float* __restrict__ kvpart) {
  __shared__ __align__(16) unsigned short kT[64 * 64];
  __shared__ __align__(16) unsigned short vT[128 * 64];
  __shared__ float cmaxs[64], cinvs[64];
  const int tid = threadIdx.x;
  const int chunk = blockIdx.x;
  const int n = blockIdx.y;
  const int b = n >> 3, h = n & 7;
  if (tid < 64) {
    cmaxs[tid] = colmax[b * E_DIM + h * 64 + tid];
    cinvs[tid] = colinv[b * E_DIM + h * 64 + tid];
  }
  const int lane = tid & 63;
  const int w = tid >> 6;
  const int lr = lane & 15;
  const int lk = (lane >> 4) * 8;
  const int sp = tid & 31;
  const int g = tid >> 5;
  f32x4 acc[4][2];
#pragma unroll
  for (int i = 0; i < 4; ++i) {
    acc[i][0] = (f32x4){0.f, 0.f, 0.f, 0.f};
    acc[i][1] = (f32x4){0.f, 0.f, 0.f, 0.f};
  }
  __syncthreads();

  for (int st = 0; st < 8; ++st) {
    int sA = chunk * 512 + st * 64 + 2 * sp;
    const unsigned short* kp = Kp + ((size_t)b * L_DIM + sA) * 512 + h * 64 + g * 8;
    uint4 ka = *(const uint4*)kp;
    uint4 kb = *(const uint4*)(kp + 512);
    int vr = ((sA >> 9) << 12) + ((sA & 511) << 3) + b;
    const unsigned short* vp = Vpb + (size_t)vr * 512 + h * 64 + g * 8;
    uint4 v0 = *(const uint4*)vp;
    uint4 v1 = *(const uint4*)(vp + 8 * 512);
    float kfa[8], kfb[8], vA[8], vB[8];
    unpk8(ka, kfa);
    unpk8(kb, kfb);
    unpk8(v0, vA);
    unpk8(v1, vB);
    float sS = sintab[sA], sC = costab[sA];
    float tS = sintab[sA + 1], tC = costab[sA + 1];
    __syncthreads();
#pragma unroll
    for (int i = 0; i < 8; ++i) {
      int d = g * 8 + i;
      float e0 = __expf(kfa[i] - cmaxs[d]) * cinvs[d];
      float e1 = __expf(kfb[i] - cmaxs[d]) * cinvs[d];
      *(unsigned int*)&kT[swz64(d, 2 * sp)] = pkbf(e0, e1);
    }
#pragma unroll
    for (int i = 0; i < 8; ++i) {
      int m = g * 8 + i;
      *(unsigned int*)&vT[swz64(m, 2 * sp)] = pkbf(vA[i] * sS, vB[i] * tS);
      *(unsigned int*)&vT[swz64(64 + m, 2 * sp)] = pkbf(vA[i] * sC, vB[i] * tC);
    }
    __syncthreads();
#pragma unroll
    for (int kk = 0; kk < 2; ++kk) {
      int ke = kk * 32 + lk;
      bf16x8 av[4], bv[2];
#pragma unroll
      for (int fm = 0; fm < 4; ++fm)
        av[fm] = *(const bf16x8*)&kT[swz64(fm * 16 + lr, ke)];
#pragma unroll
      for (int fn = 0; fn < 2; ++fn)
        bv[fn] = *(const bf16x8*)&vT[swz64(w * 32 + fn * 16 + lr, ke)];
#pragma unroll
      for (int fm = 0; fm < 4; ++fm)
#pragma unroll
        for (int fn = 0; fn < 2; ++fn)
          acc[fm][fn] = __builtin_amdgcn_mfma_f32_16x16x32_bf16(av[fm], bv[fn],
                                                                acc[fm][fn], 0, 0, 0);
    }
  }
  const int rq = lane >> 4;
#pragma unroll
  for (int fn = 0; fn < 2; ++fn) {
    int ncol = w * 32 + fn * 16 + lr;
    int m = ncol & 63;
    int ddbase = (ncol >> 6) * 64;
#pragma unroll
    for (int fm = 0; fm < 4; ++fm) {
#pragma unroll
      for (int jj = 0; jj < 4; ++jj) {
        int dd = ddbase + fm * 16 + rq * 4 + jj;
        kvpart[(((size_t)chunk * 64 + n) * 64 + m) * 128 + dd] = acc[fm][fn][jj];
      }
    }
  }
}

// reduce 8 chunks -> kvT bf16, pre-swizzled [n][m][dd']
__global__ void kv_reduce_swz(const float* __restrict__ part,
                              unsigned short* __restrict__ kvT) {
  int i = blockIdx.x * 256 + threadIdx.x;
  float s = 0.f;
#pragma unroll
  for (int c = 0; c < 8; ++c) s += part[(size_t)c * 524288 + i];
  int dd = i & 127;
  int m = (i >> 7) & 63;
  int nm = i >> 7;
  int gg = dd >> 3;
  int e = ((gg & 8) | ((gg ^ m) & 7)) * 8 + (dd & 7);
  kvT[(size_t)nm * 128 + e] = f2bf(s);
}

// ---------------------------------------------------------------------------
// Fused out pass, both terms: Yb[l][m] = sum_t sum_dd q2_t[l][dd]*kvT_t[m][dd]
// bf16 output via LDS-staged vectorized write. grid (64 lc, 64 n).
// ---------------------------------------------------------------------------
__global__ __launch_bounds__(256) void out_fused(
    const unsigned short* __restrict__ Qp0, const unsigned short* __restrict__ Qp1,
    const unsigned short* __restrict__ kvT,
    const float* __restrict__ sintab, const float* __restrict__ costab,
    unsigned short* __restrict__ Yb) {
  __shared__ __align__(16) unsigned short q2s[64 * 128];
  __shared__ __align__(16) unsigned short kvs[2][64 * 128];
  const int tid = threadIdx.x;
  const int lc = blockIdx.x;
  const int n = blockIdx.y;
  const int b = n >> 3, h = n & 7;
  const int lane = tid & 63;
  const int w = tid >> 6;
  {
    const uint4* s0 = (const uint4*)(kvT + (size_t)n * 8192);
    const uint4* s1 = (const uint4*)(kvT + 524288 + (size_t)n * 8192);
    uint4* d0 = (uint4*)kvs[0];
    uint4* d1 = (uint4*)kvs[1];
    // FIX (R4 bug): each term's tile is 1024 uint4, so 4 iterations each.
#pragma unroll
    for (int i = 0; i < 4; ++i) {
      d0[tid + i * 256] = s0[tid + i * 256];
      d1[tid + i * 256] = s1[tid + i * 256];
    }
  }
  const int l0 = lc * 64;
  const int wr = w >> 1, wc = w & 1;
  const int lr = lane & 15;
  const int lk = (lane >> 4) * 8;
  const int rq = lane >> 4;
  f32x4 acc[2][2];
  acc[0][0] = acc[0][1] = acc[1][0] = acc[1][1] = (f32x4){0.f, 0.f, 0.f, 0.f};
#pragma unroll
  for (int t = 0; t < 2; ++t) {
    const unsigned short* Qp = t ? Qp1 : Qp0;
    if (t) __syncthreads();  // t0 q2s reads complete
#pragma unroll 1
    for (int i = 0; i < 16; ++i) {
      int l = i * 4 + w;
      float x = bf2f(Qp[((size_t)b * L_DIM + l0 + l) * 512 + h * 64 + lane]);
      float m = x;
#pragma unroll
      for (int off = 32; off > 0; off >>= 1) m = fmaxf(m, __shfl_xor(m, off));
      float e = __expf(x - m);
      float ssum = e;
#pragma unroll
      for (int off = 32; off > 0; off >>= 1) ssum += __shfl_xor(ssum, off);
      float p = e / ssum;
      int gl = l0 + l;
      q2s[swz128(l, lane)] = f2bf(p * sintab[gl]);
      q2s[swz128(l, 64 + lane)] = f2bf(p * costab[gl]);
    }
    __syncthreads();
#pragma unroll
    for (int ks = 0; ks < 4; ++ks) {
      int ke = ks * 32 + lk;
      bf16x8 av[2], bv[2];
#pragma unroll
      for (int fm = 0; fm < 2; ++fm)
        av[fm] = *(const bf16x8*)&q2s[swz128(wr * 32 + fm * 16 + lr, ke)];
#pragma unroll
      for (int fn = 0; fn < 2; ++fn)
        bv[fn] = *(const bf16x8*)&kvs[t][swz128(wc * 32 + fn * 16 + lr, ke)];
#pragma unroll
      for (int fm = 0; fm < 2; ++fm)
#pragma unroll
        for (int fn = 0; fn < 2; ++fn)
          acc[fm][fn] = __builtin_amdgcn_mfma_f32_16x16x32_bf16(av[fm], bv[fn],
                                                                acc[fm][fn], 0, 0, 0);
    }
  }
  __syncthreads();
  unsigned short* Os = q2s;  // 64 x (stride 72)
#pragma unroll
  for (int fn = 0; fn < 2; ++fn) {
    int col = wc * 32 + fn * 16 + lr;
#pragma unroll
    for (int fm = 0; fm < 2; ++fm) {
      int lrow = wr * 32 + fm * 16 + rq * 4;
#pragma unroll
      for (int jj = 0; jj < 4; ++jj)
        Os[(lrow + jj) * 72 + col] = f2bf(acc[fm][fn][jj]);
    }
  }
  __syncthreads();
#pragma unroll
  for (int i = 0; i < 2; ++i) {
    int idx = tid + i * 256;
    int row = idx >> 3, g = idx & 7;
    *(uint4*)(Yb + ((size_t)b * L_DIM + l0 + row) * 512 + h * 64 + g * 8) =
        *(const uint4*)&Os[row * 72 + g * 8];
  }
}

// ---------------------------------------------------------------------------
extern "C" void kernel_launch(void* const* d_in, const int* in_sizes, int n_in,
                              void* d_out, int out_size, void* d_ws, size_t ws_size,
                              hipStream_t stream) {
  const float* query = (const float*)d_in[0];
  const float* key   = (const float*)d_in[1];
  const float* value = (const float*)d_in[2];
  const float* Wq    = (const float*)d_in[3];
  const float* bq    = (const float*)d_in[4];
  const float* Wk    = (const float*)d_in[5];
  const float* bk    = (const float*)d_in[6];
  const float* Wv    = (const float*)d_in[7];
  const float* bv    = (const float*)d_in[8];
  const float* Wout  = (const float*)d_in[9];
  const float* bout  = (const float*)d_in[10];
  float* out = (float*)d_out;
  float* ws = (float*)d_ws;

  // workspace (fp32 slot units)
  const size_t F_PROJ0 = 0;                       // 32768x512 bf16 (t0)
  const size_t F_PROJ1 = F_PROJ0 + 8388608;       // 32768x512 bf16 (t1)
  const size_t F_VPB   = F_PROJ1 + 8388608;       // V proj bf16
  const size_t F_KVP   = F_VPB + 8388608;         // kv partials fp32
  const size_t F_KVT   = F_KVP + 4194304;         // kvT bf16, 2 terms
  const size_t F_XBUF  = F_KVT + 524288;          // attn-out bf16
  const size_t F_WBF   = F_XBUF + 8388608;        // weights bf16
  const size_t F_CMAX  = F_WBF + 786432;
  const size_t F_CINV  = F_CMAX + 4096;
  const size_t F_SIN   = F_CINV + 4096;
  const size_t F_COS   = F_SIN + 4096;
  const size_t TOTALF  = F_COS + 4096;
  if (ws_size < TOTALF * sizeof(float)) {
    fprintf(stderr, "kernel_launch: ws too small (%zu < %zu)\n", ws_size, TOTALF * 4);
    return;
  }
  unsigned short* proj0 = (unsigned short*)(ws + F_PROJ0);
  unsigned short* vpb   = (unsigned short*)(ws + F_VPB);
  float* kvpart = ws + F_KVP;
  unsigned short* kvT  = (unsigned short*)(ws + F_KVT);
  unsigned short* xbuf = (unsigned short*)(ws + F_XBUF);
  unsigned short* wbf  = (unsigned short*)(ws + F_WBF);
  float* cmax = ws + F_CMAX;
  float* cinv = ws + F_CINV;
  float* sintab = ws + F_SIN;
  float* costab = ws + F_COS;
  float* pmax = kvpart;           // disjoint lifetime aliases
  float* psum = kvpart + 131072;
  const size_t WQ_O = 0, WK_O = 524288, WV_O = 1048576, WOUT_O = 1310720;

  sincos_kernel<<<16, 256, 0, stream>>>(sintab, costab);
  convf2b<<<256, 256, 0, stream>>>(Wq, wbf + WQ_O, 65536);
  convf2b<<<256, 256, 0, stream>>>(Wk, wbf + WK_O, 65536);
  convf2b<<<128, 256, 0, stream>>>(Wv, wbf + WV_O, 32768);
  convf2b<<<128, 256, 0, stream>>>(Wout, wbf + WOUT_O, 32768);

  // V projection: fp32 A, bf16 out
  gemm_xwt<true, false, 2><<<1024, 256, 0, stream>>>(value, wbf + WV_O, bv, vpb);

  // K projections, both terms in one N=1024 GEMM (key read once)
  gemm_xwt<true, false, 3><<<2048, 256, 0, stream>>>(key, wbf + WK_O, bk, proj0);
  for (int t = 0; t < T_DIM; ++t) {
    unsigned short* projt = proj0 + (size_t)t * YHALF;
    kcolstats_part<<<dim3(8, 8, 32), dim3(64, 4), 0, stream>>>(projt, pmax, psum);
    kcolstats_reduce<<<16, 256, 0, stream>>>(pmax, psum, cmax, cinv);
    kv_mfma<<<dim3(8, 64), 256, 0, stream>>>(projt, vpb, cmax, cinv,
                                             sintab, costab, kvpart);
    kv_reduce_swz<<<2048, 256, 0, stream>>>(kvpart, kvT + (size_t)t * 524288);
  }

  // Q projections, both terms in one N=1024 GEMM (query read once)
  gemm_xwt<true, false, 3><<<2048, 256, 0, stream>>>(query, wbf + WQ_O, bq, proj0);
  // fused output accumulation over both terms -> xbuf (bf16)
  out_fused<<<dim3(64, 64), 256, 0, stream>>>(proj0, proj0 + YHALF, kvT,
                                              sintab, costab, xbuf);
  // final projection: bf16 A, fp32 out
  gemm_xwt<false, true, 2><<<1024, 256, 0, stream>>>(xbuf, wbf + WOUT_O, bout, out);
}

// Round 6
// 559.403 us; speedup vs baseline: 1.5743x; 1.1901x over previous
//
#include <hip/hip_runtime.h>
#include <cstdio>

#define E_DIM 512
#define L_DIM 4096
#define B_DIM 8
#define H_DIM 8
#define T_DIM 2
#define M_ROWS 32768

typedef __attribute__((ext_vector_type(8))) __bf16 bf16x8;
typedef __attribute__((ext_vector_type(4))) float f32x4;

static __device__ __forceinline__ unsigned short f2bf(float f) {
  unsigned int u = __float_as_uint(f);
  return (unsigned short)((u + 0x7FFFu + ((u >> 16) & 1u)) >> 16);
}
static __device__ __forceinline__ unsigned int pkbf(float lo, float hi) {
  return (unsigned int)f2bf(lo) | ((unsigned int)f2bf(hi) << 16);
}
static __device__ __forceinline__ float bf2f(unsigned short u) {
  return __uint_as_float((unsigned int)u << 16);
}
static __device__ __forceinline__ void unpk8(uint4 u, float* f) {
  f[0] = bf2f((unsigned short)u.x); f[1] = bf2f((unsigned short)(u.x >> 16));
  f[2] = bf2f((unsigned short)u.y); f[3] = bf2f((unsigned short)(u.y >> 16));
  f[4] = bf2f((unsigned short)u.z); f[5] = bf2f((unsigned short)(u.z >> 16));
  f[6] = bf2f((unsigned short)u.w); f[7] = bf2f((unsigned short)(u.w >> 16));
}
// XOR swizzle at 8-elem (16B) granules
static __device__ __forceinline__ int swz64(int row, int e) {
  return row * 64 + ((((e >> 3) ^ row) & 7) << 3) + (e & 7);
}
static __device__ __forceinline__ int swz128(int row, int e) {
  return row * 128 + ((((e >> 3) ^ row) & 7) << 3) + ((e >> 3) & 8) * 8 + (e & 7);
}

// ---------------------------------------------------------------------------
__global__ void sincos_kernel(float* __restrict__ sintab, float* __restrict__ costab) {
  int i = blockIdx.x * blockDim.x + threadIdx.x;
  if (i < L_DIM) {
    float idx = 1.57079632679489662f * (float)(i + 1) / (float)L_DIM;
    sintab[i] = sinf(idx);
    costab[i] = cosf(idx);
  }
}

__global__ void convf2b(const float* __restrict__ src, unsigned short* __restrict__ dst,
                        int n8) {
  for (int i = blockIdx.x * blockDim.x + threadIdx.x; i < n8; i += gridDim.x * blockDim.x) {
    float4 a = *(const float4*)(src + (size_t)i * 8);
    float4 b = *(const float4*)(src + (size_t)i * 8 + 4);
    uint4 o;
    o.x = pkbf(a.x, a.y); o.y = pkbf(a.z, a.w);
    o.z = pkbf(b.x, b.y); o.w = pkbf(b.z, b.w);
    *(uint4*)(dst + (size_t)i * 8) = o;
  }
}

// ---------------------------------------------------------------------------
// Y[M][N] = X[M][512] @ W[N][512]^T + bias[N]; N = 512<<(NBL2-2).
// (unchanged from R5 — passing)
// ---------------------------------------------------------------------------
#define YHALF 16777216
template <bool AF32, bool OUTF32, int NBL2>
__global__ __launch_bounds__(256) void gemm_xwt(
    const void* __restrict__ Xv, const unsigned short* __restrict__ W,
    const float* __restrict__ bias, void* __restrict__ Yv) {
  __shared__ __align__(16) unsigned short smem[17408];
  unsigned short* As = smem;          // 128x64
  unsigned short* Bs = smem + 8192;   // 128x64
  const int tid = threadIdx.x;
  const int id = blockIdx.x;
  const int j = id >> 3;
  const int mb = (id & 7) * 32 + (j >> NBL2);
  const int nb = j & ((1 << NBL2) - 1);
  const int m0 = mb * 128, n0 = nb * 128;
  const int lane = tid & 63;
  const int w = tid >> 6;
  const int wr = w >> 1, wc = w & 1;
  const int lr = lane & 15;
  const int lk = (lane >> 4) * 8;
  f32x4 acc[4][4];
#pragma unroll
  for (int i = 0; i < 4; ++i)
#pragma unroll
    for (int jj = 0; jj < 4; ++jj) acc[i][jj] = (f32x4){0.f, 0.f, 0.f, 0.f};

  for (int k0 = 0; k0 < 512; k0 += 64) {
    uint4 va[4], vb[4];
#pragma unroll
    for (int i = 0; i < 4; ++i) {
      int gi = tid + i * 256;
      int r = gi >> 3, g = gi & 7;
      if (AF32) {
        const float* pa = (const float*)Xv + (size_t)(m0 + r) * 512 + k0 + g * 8;
        float4 a0 = *(const float4*)pa;
        float4 a1 = *(const float4*)(pa + 4);
        uint4 o;
        o.x = pkbf(a0.x, a0.y); o.y = pkbf(a0.z, a0.w);
        o.z = pkbf(a1.x, a1.y); o.w = pkbf(a1.z, a1.w);
        va[i] = o;
      } else {
        va[i] = *(const uint4*)((const unsigned short*)Xv +
                                (size_t)(m0 + r) * 512 + k0 + g * 8);
      }
      vb[i] = *(const uint4*)(W + (size_t)(n0 + r) * 512 + k0 + g * 8);
    }
    __syncthreads();
#pragma unroll
    for (int i = 0; i < 4; ++i) {
      int gi = tid + i * 256;
      int r = gi >> 3, g = gi & 7;
      int off = r * 64 + ((g ^ (r & 7)) << 3);
      *(uint4*)&As[off] = va[i];
      *(uint4*)&Bs[off] = vb[i];
    }
    __syncthreads();
#pragma unroll
    for (int kk = 0; kk < 2; ++kk) {
      bf16x8 av[4], bv[4];
      int ke = kk * 32 + lk;
#pragma unroll
      for (int fm = 0; fm < 4; ++fm)
        av[fm] = *(const bf16x8*)&As[swz64(wr * 64 + fm * 16 + lr, ke)];
#pragma unroll
      for (int fn = 0; fn < 4; ++fn)
        bv[fn] = *(const bf16x8*)&Bs[swz64(wc * 64 + fn * 16 + lr, ke)];
#pragma unroll
      for (int fm = 0; fm < 4; ++fm)
#pragma unroll
        for (int fn = 0; fn < 4; ++fn)
          acc[fm][fn] = __builtin_amdgcn_mfma_f32_16x16x32_bf16(av[fm], bv[fn],
                                                                acc[fm][fn], 0, 0, 0);
    }
  }
  __syncthreads();  // staging reads done; smem becomes epilogue tile
  const int rq = lane >> 4;
  if (!OUTF32) {
    unsigned short* Cs = smem;  // 128 x (stride 136)
#pragma unroll
    for (int fn = 0; fn < 4; ++fn) {
      int col = wc * 64 + fn * 16 + lr;
      float bb = bias[n0 + col];
#pragma unroll
      for (int fm = 0; fm < 4; ++fm) {
        int row = wr * 64 + fm * 16 + rq * 4;
#pragma unroll
        for (int jj = 0; jj < 4; ++jj)
          Cs[(row + jj) * 136 + col] = f2bf(acc[fm][fn][jj] + bb);
      }
    }
    __syncthreads();
    unsigned short* Yb = (unsigned short*)Yv + (size_t)(n0 >> 9) * YHALF;
    const int nc = n0 & 511;
#pragma unroll
    for (int i = 0; i < 8; ++i) {
      int idx = tid + i * 256;     // 0..2047
      int row = idx >> 4, g = idx & 15;
      *(uint4*)(Yb + (size_t)(m0 + row) * 512 + nc + g * 8) =
          *(const uint4*)&Cs[row * 136 + g * 8];
    }
  } else {
    float* Cf = (float*)smem;  // 64 x (stride 132)
    float* Yf = (float*)Yv;
#pragma unroll
    for (int p = 0; p < 2; ++p) {
      if (p) __syncthreads();
      if (wr == p) {
#pragma unroll
        for (int fn = 0; fn < 4; ++fn) {
          int col = wc * 64 + fn * 16 + lr;
          float bb = bias[n0 + col];
#pragma unroll
          for (int fm = 0; fm < 4; ++fm) {
            int lrow = fm * 16 + rq * 4;
#pragma unroll
            for (int jj = 0; jj < 4; ++jj)
              Cf[(lrow + jj) * 132 + col] = acc[fm][fn][jj] + bb;
          }
        }
      }
      __syncthreads();
#pragma unroll
      for (int i = 0; i < 8; ++i) {
        int idx = tid + i * 256;
        int row = idx >> 5, g = idx & 31;
        *(float4*)(Yf + (size_t)(m0 + p * 64 + row) * 512 + n0 + g * 4) =
            *(const float4*)&Cf[row * 132 + g * 4];
      }
    }
  }
}

// ---------------------------------------------------------------------------
// k softmax column stats: vectorized two-pass (max, then exp-sum on L2-hot
// data). Block (64 granules x 4 s-strips) covers all 512 f for one
// (b, 128-row chunk). grid (8 b, 32 chunks).
// ---------------------------------------------------------------------------
__global__ __launch_bounds__(256) void kcolstats_part(
    const unsigned short* __restrict__ Kp, float* __restrict__ pmax,
    float* __restrict__ psum) {
  int b = blockIdx.x;
  int chunk = blockIdx.y;
  int gx = threadIdx.x;   // granule 0..63 -> f = gx*8..+7
  int sy = threadIdx.y;   // strip 0..3
  const unsigned short* base = Kp + ((size_t)b * L_DIM + chunk * 128) * 512 + gx * 8;
  __shared__ float red[4][512];
  float m[8];
#pragma unroll
  for (int k = 0; k < 8; ++k) m[k] = -3.0e38f;
  for (int s = sy; s < 128; s += 4) {
    uint4 q = *(const uint4*)(base + (size_t)s * 512);
    float v[8];
    unpk8(q, v);
#pragma unroll
    for (int k = 0; k < 8; ++k) m[k] = fmaxf(m[k], v[k]);
  }
  *(float4*)&red[sy][gx * 8] = make_float4(m[0], m[1], m[2], m[3]);
  *(float4*)&red[sy][gx * 8 + 4] = make_float4(m[4], m[5], m[6], m[7]);
  __syncthreads();
#pragma unroll
  for (int k = 0; k < 8; ++k) {
    int f = gx * 8 + k;
    m[k] = fmaxf(fmaxf(red[0][f], red[1][f]), fmaxf(red[2][f], red[3][f]));
  }
  __syncthreads();  // red reused for sums
  float sum[8];
#pragma unroll
  for (int k = 0; k < 8; ++k) sum[k] = 0.f;
  for (int s = sy; s < 128; s += 4) {
    uint4 q = *(const uint4*)(base + (size_t)s * 512);
    float v[8];
    unpk8(q, v);
#pragma unroll
    for (int k = 0; k < 8; ++k) sum[k] += __expf(v[k] - m[k]);
  }
  *(float4*)&red[sy][gx * 8] = make_float4(sum[0], sum[1], sum[2], sum[3]);
  *(float4*)&red[sy][gx * 8 + 4] = make_float4(sum[4], sum[5], sum[6], sum[7]);
  __syncthreads();
  if (sy == 0) {
#pragma unroll
    for (int k = 0; k < 8; ++k) {
      int f = gx * 8 + k;
      float s = (red[0][f] + red[1][f]) + (red[2][f] + red[3][f]);
      pmax[(size_t)chunk * 4096 + b * E_DIM + f] = m[k];
      psum[(size_t)chunk * 4096 + b * E_DIM + f] = s;
    }
  }
}

__global__ void kcolstats_reduce(const float* __restrict__ pmax,
                                 const float* __restrict__ psum,
                                 float* __restrict__ colmax,
                                 float* __restrict__ colinv) {
  int i = blockIdx.x * 256 + threadIdx.x;
  float M = -3.0e38f, S = 0.f;
#pragma unroll
  for (int c = 0; c < 32; ++c) {
    float m = pmax[(size_t)c * 4096 + i];
    float s = psum[(size_t)c * 4096 + i];
    float nm = fmaxf(M, m);
    S = S * __expf(M - nm) + s * __expf(m - nm);
    M = nm;
  }
  colmax[i] = M;
  colinv[i] = 1.f / S;
}

// ---------------------------------------------------------------------------
// kv partials via MFMA (unchanged from R5 — passing)
// ---------------------------------------------------------------------------
__global__ __launch_bounds__(256) void kv_mfma(
    const unsigned short* __restrict__ Kp, const unsigned short* __restrict__ Vpb,
    const float* __restrict__ colmax, const float* __restrict__ colinv,
    const float* __restrict__ sintab, const float* __restrict__ costab,
    float* __restrict__ kvpart) {
  __shared__ __align__(16) unsigned short kT[64 * 64];
  __shared__ __align__(16) unsigned short vT[128 * 64];
  __shared__ float cmaxs[64], cinvs[64];
  const int tid = threadIdx.x;
  const int chunk = blockIdx.x;
  const int n = blockIdx.y;
  const int b = n >> 3, h = n & 7;
  if (tid < 64) {
    cmaxs[tid] = colmax[b * E_DIM + h * 64 + tid];
    cinvs[tid] = colinv[b * E_DIM + h * 64 + tid];
  }
  const int lane = tid & 63;
  const int w = tid >> 6;
  const int lr = lane & 15;
  const int lk = (lane >> 4) * 8;
  const int sp = tid & 31;
  const int g = tid >> 5;
  f32x4 acc[4][2];
#pragma unroll
  for (int i = 0; i < 4; ++i) {
    acc[i][0] = (f32x4){0.f, 0.f, 0.f, 0.f};
    acc[i][1] = (f32x4){0.f, 0.f, 0.f, 0.f};
  }
  __syncthreads();

  for (int st = 0; st < 8; ++st) {
    int sA = chunk * 512 + st * 64 + 2 * sp;
    const unsigned short* kp = Kp + ((size_t)b * L_DIM + sA) * 512 + h * 64 + g * 8;
    uint4 ka = *(const uint4*)kp;
    uint4 kb = *(const uint4*)(kp + 512);
    int vr = ((sA >> 9) << 12) + ((sA & 511) << 3) + b;
    const unsigned short* vp = Vpb + (size_t)vr * 512 + h * 64 + g * 8;
    uint4 v0 = *(const uint4*)vp;
    uint4 v1 = *(const uint4*)(vp + 8 * 512);
    float kfa[8], kfb[8], vA[8], vB[8];
    unpk8(ka, kfa);
    unpk8(kb, kfb);
    unpk8(v0, vA);
    unpk8(v1, vB);
    float sS = sintab[sA], sC = costab[sA];
    float tS = sintab[sA + 1], tC = costab[sA + 1];
    __syncthreads();
#pragma unroll
    for (int i = 0; i < 8; ++i) {
      int d = g * 8 + i;
      float e0 = __expf(kfa[i] - cmaxs[d]) * cinvs[d];
      float e1 = __expf(kfb[i] - cmaxs[d]) * cinvs[d];
      *(unsigned int*)&kT[swz64(d, 2 * sp)] = pkbf(e0, e1);
    }
#pragma unroll
    for (int i = 0; i < 8; ++i) {
      int m = g * 8 + i;
      *(unsigned int*)&vT[swz64(m, 2 * sp)] = pkbf(vA[i] * sS, vB[i] * tS);
      *(unsigned int*)&vT[swz64(64 + m, 2 * sp)] = pkbf(vA[i] * sC, vB[i] * tC);
    }
    __syncthreads();
#pragma unroll
    for (int kk = 0; kk < 2; ++kk) {
      int ke = kk * 32 + lk;
      bf16x8 av[4], bv[2];
#pragma unroll
      for (int fm = 0; fm < 4; ++fm)
        av[fm] = *(const bf16x8*)&kT[swz64(fm * 16 + lr, ke)];
#pragma unroll
      for (int fn = 0; fn < 2; ++fn)
        bv[fn] = *(const bf16x8*)&vT[swz64(w * 32 + fn * 16 + lr, ke)];
#pragma unroll
      for (int fm = 0; fm < 4; ++fm)
#pragma unroll
        for (int fn = 0; fn < 2; ++fn)
          acc[fm][fn] = __builtin_amdgcn_mfma_f32_16x16x32_bf16(av[fm], bv[fn],
                                                                acc[fm][fn], 0, 0, 0);
    }
  }
  const int rq = lane >> 4;
#pragma unroll
  for (int fn = 0; fn < 2; ++fn) {
    int ncol = w * 32 + fn * 16 + lr;
    int m = ncol & 63;
    int ddbase = (ncol >> 6) * 64;
#pragma unroll
    for (int fm = 0; fm < 4; ++fm) {
#pragma unroll
      for (int jj = 0; jj < 4; ++jj) {
        int dd = ddbase + fm * 16 + rq * 4 + jj;
        kvpart[(((size_t)chunk * 64 + n) * 64 + m) * 128 + dd] = acc[fm][fn][jj];
      }
    }
  }
}

// reduce 8 chunks -> kvT bf16, pre-swizzled [n][m][dd']
__global__ void kv_reduce_swz(const float* __restrict__ part,
                              unsigned short* __restrict__ kvT) {
  int i = blockIdx.x * 256 + threadIdx.x;
  float s = 0.f;
#pragma unroll
  for (int c = 0; c < 8; ++c) s += part[(size_t)c * 524288 + i];
  int dd = i & 127;
  int m = (i >> 7) & 63;
  int nm = i >> 7;
  int gg = dd >> 3;
  int e = ((gg & 8) | ((gg ^ m) & 7)) * 8 + (dd & 7);
  kvT[(size_t)nm * 128 + e] = f2bf(s);
}

// ---------------------------------------------------------------------------
// Fused out pass, both terms: Yb[l][m] = sum_t sum_dd q2_t[l][dd]*kvT_t[m][dd]
// R6: vectorized Q loads (uint4, 8 lanes per 64-wide head row), softmax via
// 8-lane-group shfl reduce, 1/sum folded into sin/cos scale, packed uint4
// swizzled LDS writes. grid (64 lc, 64 n).
// ---------------------------------------------------------------------------
__global__ __launch_bounds__(256) void out_fused(
    const unsigned short* __restrict__ Qp0, const unsigned short* __restrict__ Qp1,
    const unsigned short* __restrict__ kvT,
    const float* __restrict__ sintab, const float* __restrict__ costab,
    unsigned short* __restrict__ Yb) {
  __shared__ __align__(16) unsigned short q2s[64 * 128];
  __shared__ __align__(16) unsigned short kvs[2][64 * 128];
  const int tid = threadIdx.x;
  const int lc = blockIdx.x;
  const int n = blockIdx.y;
  const int b = n >> 3, h = n & 7;
  const int lane = tid & 63;
  const int w = tid >> 6;
  {
    const uint4* s0 = (const uint4*)(kvT + (size_t)n * 8192);
    const uint4* s1 = (const uint4*)(kvT + 524288 + (size_t)n * 8192);
    uint4* d0 = (uint4*)kvs[0];
    uint4* d1 = (uint4*)kvs[1];
#pragma unroll
    for (int i = 0; i < 4; ++i) {
      d0[tid + i * 256] = s0[tid + i * 256];
      d1[tid + i * 256] = s1[tid + i * 256];
    }
  }
  const int l0 = lc * 64;
  const int wr = w >> 1, wc = w & 1;
  const int lr = lane & 15;
  const int lk = (lane >> 4) * 8;
  const int rq = lane >> 4;
  f32x4 acc[2][2];
  acc[0][0] = acc[0][1] = acc[1][0] = acc[1][1] = (f32x4){0.f, 0.f, 0.f, 0.f};
#pragma unroll
  for (int t = 0; t < 2; ++t) {
    const unsigned short* Qp = t ? Qp1 : Qp0;
    if (t) __syncthreads();  // t0 q2s reads complete
#pragma unroll
    for (int i = 0; i < 2; ++i) {
      int idx = tid + i * 256;      // 0..511
      int row = idx >> 3;           // 0..63
      int g = idx & 7;              // granule within the 64-wide head row
      uint4 q = *(const uint4*)(Qp + ((size_t)b * L_DIM + l0 + row) * 512 +
                                h * 64 + g * 8);
      float v[8];
      unpk8(q, v);
      float m8 = fmaxf(fmaxf(fmaxf(v[0], v[1]), fmaxf(v[2], v[3])),
                       fmaxf(fmaxf(v[4], v[5]), fmaxf(v[6], v[7])));
      // lanes (tid&7)=g share a row: reduce across the 8-lane group
      m8 = fmaxf(m8, __shfl_xor(m8, 1));
      m8 = fmaxf(m8, __shfl_xor(m8, 2));
      m8 = fmaxf(m8, __shfl_xor(m8, 4));
      float e[8], s8;
#pragma unroll
      for (int k = 0; k < 8; ++k) e[k] = __expf(v[k] - m8);
      s8 = ((e[0] + e[1]) + (e[2] + e[3])) + ((e[4] + e[5]) + (e[6] + e[7]));
      s8 += __shfl_xor(s8, 1);
      s8 += __shfl_xor(s8, 2);
      s8 += __shfl_xor(s8, 4);
      float inv = 1.f / s8;
      int gl = l0 + row;
      float sn = sintab[gl] * inv;
      float cs = costab[gl] * inv;
      uint4 os, oc;
      os.x = pkbf(e[0] * sn, e[1] * sn); os.y = pkbf(e[2] * sn, e[3] * sn);
      os.z = pkbf(e[4] * sn, e[5] * sn); os.w = pkbf(e[6] * sn, e[7] * sn);
      oc.x = pkbf(e[0] * cs, e[1] * cs); oc.y = pkbf(e[2] * cs, e[3] * cs);
      oc.z = pkbf(e[4] * cs, e[5] * cs); oc.w = pkbf(e[6] * cs, e[7] * cs);
      *(uint4*)&q2s[swz128(row, g * 8)] = os;
      *(uint4*)&q2s[swz128(row, 64 + g * 8)] = oc;
    }
    __syncthreads();
#pragma unroll
    for (int ks = 0; ks < 4; ++ks) {
      int ke = ks * 32 + lk;
      bf16x8 av[2], bv[2];
#pragma unroll
      for (int fm = 0; fm < 2; ++fm)
        av[fm] = *(const bf16x8*)&q2s[swz128(wr * 32 + fm * 16 + lr, ke)];
#pragma unroll
      for (int fn = 0; fn < 2; ++fn)
        bv[fn] = *(const bf16x8*)&kvs[t][swz128(wc * 32 + fn * 16 + lr, ke)];
#pragma unroll
      for (int fm = 0; fm < 2; ++fm)
#pragma unroll
        for (int fn = 0; fn < 2; ++fn)
          acc[fm][fn] = __builtin_amdgcn_mfma_f32_16x16x32_bf16(av[fm], bv[fn],
                                                                acc[fm][fn], 0, 0, 0);
    }
  }
  __syncthreads();
  unsigned short* Os = q2s;  // 64 x (stride 72)
#pragma unroll
  for (int fn = 0; fn < 2; ++fn) {
    int col = wc * 32 + fn * 16 + lr;
#pragma unroll
    for (int fm = 0; fm < 2; ++fm) {
      int lrow = wr * 32 + fm * 16 + rq * 4;
#pragma unroll
      for (int jj = 0; jj < 4; ++jj)
        Os[(lrow + jj) * 72 + col] = f2bf(acc[fm][fn][jj]);
    }
  }
  __syncthreads();
#pragma unroll
  for (int i = 0; i < 2; ++i) {
    int idx = tid + i * 256;
    int row = idx >> 3, g = idx & 7;
    *(uint4*)(Yb + ((size_t)b * L_DIM + l0 + row) * 512 + h * 64 + g * 8) =
        *(const uint4*)&Os[row * 72 + g * 8];
  }
}

// ---------------------------------------------------------------------------
extern "C" void kernel_launch(void* const* d_in, const int* in_sizes, int n_in,
                              void* d_out, int out_size, void* d_ws, size_t ws_size,
                              hipStream_t stream) {
  const float* query = (const float*)d_in[0];
  const float* key   = (const float*)d_in[1];
  const float* value = (const float*)d_in[2];
  const float* Wq    = (const float*)d_in[3];
  const float* bq    = (const float*)d_in[4];
  const float* Wk    = (const float*)d_in[5];
  const float* bk    = (const float*)d_in[6];
  const float* Wv    = (const float*)d_in[7];
  const float* bv    = (const float*)d_in[8];
  const float* Wout  = (const float*)d_in[9];
  const float* bout  = (const float*)d_in[10];
  float* out = (float*)d_out;
  float* ws = (float*)d_ws;

  // workspace (fp32 slot units)
  const size_t F_PROJ0 = 0;                       // 32768x512 bf16 (t0)
  const size_t F_PROJ1 = F_PROJ0 + 8388608;       // 32768x512 bf16 (t1)
  const size_t F_VPB   = F_PROJ1 + 8388608;       // V proj bf16
  const size_t F_KVP   = F_VPB + 8388608;         // kv partials fp32
  const size_t F_KVT   = F_KVP + 4194304;         // kvT bf16, 2 terms
  const size_t F_XBUF  = F_KVT + 524288;          // attn-out bf16
  const size_t F_WBF   = F_XBUF + 8388608;        // weights bf16
  const size_t F_CMAX  = F_WBF + 786432;
  const size_t F_CINV  = F_CMAX + 4096;
  const size_t F_SIN   = F_CINV + 4096;
  const size_t F_COS   = F_SIN + 4096;
  const size_t TOTALF  = F_COS + 4096;
  if (ws_size < TOTALF * sizeof(float)) {
    fprintf(stderr, "kernel_launch: ws too small (%zu < %zu)\n", ws_size, TOTALF * 4);
    return;
  }
  unsigned short* proj0 = (unsigned short*)(ws + F_PROJ0);
  unsigned short* vpb   = (unsigned short*)(ws + F_VPB);
  float* kvpart = ws + F_KVP;
  unsigned short* kvT  = (unsigned short*)(ws + F_KVT);
  unsigned short* xbuf = (unsigned short*)(ws + F_XBUF);
  unsigned short* wbf  = (unsigned short*)(ws + F_WBF);
  float* cmax = ws + F_CMAX;
  float* cinv = ws + F_CINV;
  float* sintab = ws + F_SIN;
  float* costab = ws + F_COS;
  float* pmax = kvpart;           // disjoint lifetime aliases
  float* psum = kvpart + 131072;
  const size_t WQ_O = 0, WK_O = 524288, WV_O = 1048576, WOUT_O = 1310720;

  sincos_kernel<<<16, 256, 0, stream>>>(sintab, costab);
  convf2b<<<256, 256, 0, stream>>>(Wq, wbf + WQ_O, 65536);
  convf2b<<<256, 256, 0, stream>>>(Wk, wbf + WK_O, 65536);
  convf2b<<<128, 256, 0, stream>>>(Wv, wbf + WV_O, 32768);
  convf2b<<<128, 256, 0, stream>>>(Wout, wbf + WOUT_O, 32768);

  // V projection: fp32 A, bf16 out
  gemm_xwt<true, false, 2><<<1024, 256, 0, stream>>>(value, wbf + WV_O, bv, vpb);

  // K projections, both terms in one N=1024 GEMM (key read once)
  gemm_xwt<true, false, 3><<<2048, 256, 0, stream>>>(key, wbf + WK_O, bk, proj0);
  for (int t = 0; t < T_DIM; ++t) {
    unsigned short* projt = proj0 + (size_t)t * YHALF;
    kcolstats_part<<<dim3(8, 32), dim3(64, 4), 0, stream>>>(projt, pmax, psum);
    kcolstats_reduce<<<16, 256, 0, stream>>>(pmax, psum, cmax, cinv);
    kv_mfma<<<dim3(8, 64), 256, 0, stream>>>(projt, vpb, cmax, cinv,
                                             sintab, costab, kvpart);
    kv_reduce_swz<<<2048, 256, 0, stream>>>(kvpart, kvT + (size_t)t * 524288);
  }

  // Q projections, both terms in one N=1024 GEMM (query read once)
  gemm_xwt<true, false, 3><<<2048, 256, 0, stream>>>(query, wbf + WQ_O, bq, proj0);
  // fused output accumulation over both terms -> xbuf (bf16)
  out_fused<<<dim3(64, 64), 256, 0, stream>>>(proj0, proj0 + YHALF, kvT,
                                              sintab, costab, xbuf);
  // final projection: bf16 A, fp32 out
  gemm_xwt<false, true, 2><<<1024, 256, 0, stream>>>(xbuf, wbf + WOUT_O, bout, out);
}

// Round 7
// 364.559 us; speedup vs baseline: 2.4157x; 1.5345x over previous
//
#include <hip/hip_runtime.h>
#include <cstdio>

#define E_DIM 512
#define L_DIM 4096
#define B_DIM 8
#define H_DIM 8
#define T_DIM 2
#define M_ROWS 32768

typedef __attribute__((ext_vector_type(8))) __bf16 bf16x8;
typedef __attribute__((ext_vector_type(4))) float f32x4;

static __device__ __forceinline__ unsigned short f2bf(float f) {
  unsigned int u = __float_as_uint(f);
  return (unsigned short)((u + 0x7FFFu + ((u >> 16) & 1u)) >> 16);
}
static __device__ __forceinline__ unsigned int pkbf(float lo, float hi) {
  return (unsigned int)f2bf(lo) | ((unsigned int)f2bf(hi) << 16);
}
static __device__ __forceinline__ float bf2f(unsigned short u) {
  return __uint_as_float((unsigned int)u << 16);
}
static __device__ __forceinline__ void unpk8(uint4 u, float* f) {
  f[0] = bf2f((unsigned short)u.x); f[1] = bf2f((unsigned short)(u.x >> 16));
  f[2] = bf2f((unsigned short)u.y); f[3] = bf2f((unsigned short)(u.y >> 16));
  f[4] = bf2f((unsigned short)u.z); f[5] = bf2f((unsigned short)(u.z >> 16));
  f[6] = bf2f((unsigned short)u.w); f[7] = bf2f((unsigned short)(u.w >> 16));
}
// XOR swizzle at 8-elem (16B) granules
static __device__ __forceinline__ int swz64(int row, int e) {
  return row * 64 + ((((e >> 3) ^ row) & 7) << 3) + (e & 7);
}
static __device__ __forceinline__ int swz128(int row, int e) {
  return row * 128 + ((((e >> 3) ^ row) & 7) << 3) + ((e >> 3) & 8) * 8 + (e & 7);
}
// async global->LDS, 16B per lane; LDS dest = wave-uniform base + lane*16
static __device__ __forceinline__ void gl_lds16(const unsigned short* g,
                                                unsigned short* l) {
  __builtin_amdgcn_global_load_lds(
      (const __attribute__((address_space(1))) unsigned int*)g,
      (__attribute__((address_space(3))) unsigned int*)l, 16, 0, 0);
}

// ---------------------------------------------------------------------------
__global__ void sincos_kernel(float* __restrict__ sintab, float* __restrict__ costab) {
  int i = blockIdx.x * blockDim.x + threadIdx.x;
  if (i < L_DIM) {
    float idx = 1.57079632679489662f * (float)(i + 1) / (float)L_DIM;
    sintab[i] = sinf(idx);
    costab[i] = cosf(idx);
  }
}

__global__ void convf2b(const float* __restrict__ src, unsigned short* __restrict__ dst,
                        int n8) {
  for (int i = blockIdx.x * blockDim.x + threadIdx.x; i < n8; i += gridDim.x * blockDim.x) {
    float4 a = *(const float4*)(src + (size_t)i * 8);
    float4 b = *(const float4*)(src + (size_t)i * 8 + 4);
    uint4 o;
    o.x = pkbf(a.x, a.y); o.y = pkbf(a.z, a.w);
    o.z = pkbf(b.x, b.y); o.w = pkbf(b.z, b.w);
    *(uint4*)(dst + (size_t)i * 8) = o;
  }
}

// ---------------------------------------------------------------------------
// Y[M][N] = X[M][512] @ W[N][512]^T + bias[N]; N = 512<<(NBL2-2).
// bf16 X and W. Staging via global_load_lds (linear LDS dest, inverse-XOR
// pre-swizzled global source), single-buffer 2-barrier K-loop (m97 struct).
// Out bf16 (split buffers at n=512, stride YHALF) or fp32, LDS-staged epilogue.
// ---------------------------------------------------------------------------
#define YHALF 16777216
template <bool OUTF32, int NBL2>
__global__ __launch_bounds__(256) void gemm_xwt(
    const unsigned short* __restrict__ X, const unsigned short* __restrict__ W,
    const float* __restrict__ bias, void* __restrict__ Yv) {
  __shared__ __align__(16) unsigned short smem[17408];
  unsigned short* As = smem;          // 128x64 linear
  unsigned short* Bs = smem + 8192;   // 128x64 linear
  const int tid = threadIdx.x;
  const int id = blockIdx.x;
  const int j = id >> 3;
  const int mb = (id & 7) * 32 + (j >> NBL2);
  const int nb = j & ((1 << NBL2) - 1);
  const int m0 = mb * 128, n0 = nb * 128;
  const int lane = tid & 63;
  const int w = tid >> 6;
  const int wr = w >> 1, wc = w & 1;
  const int lr = lane & 15;
  const int lk = (lane >> 4) * 8;
  // staging geometry: wave w covers rows w*32..+31, 8 rows per instruction
  const int srow_off = lane >> 3;        // 0..7
  const int sp = lane & 7;               // granule position in LDS
  f32x4 acc[4][4];
#pragma unroll
  for (int i = 0; i < 4; ++i)
#pragma unroll
    for (int jj = 0; jj < 4; ++jj) acc[i][jj] = (f32x4){0.f, 0.f, 0.f, 0.f};

  for (int k0 = 0; k0 < 512; k0 += 64) {
    __syncthreads();  // all waves done reading As/Bs from previous step
#pragma unroll
    for (int i = 0; i < 4; ++i) {
      int rb = w * 32 + i * 8;
      int row = rb + srow_off;
      int gsrc = sp ^ (row & 7);          // inverse of swz64 (involution)
      gl_lds16(X + (size_t)(m0 + row) * 512 + k0 + gsrc * 8, &As[rb * 64]);
      gl_lds16(W + (size_t)(n0 + row) * 512 + k0 + gsrc * 8, &Bs[rb * 64]);
    }
    __syncthreads();  // implicit vmcnt(0) drain before barrier -> tile ready
#pragma unroll
    for (int kk = 0; kk < 2; ++kk) {
      bf16x8 av[4], bv[4];
      int ke = kk * 32 + lk;
#pragma unroll
      for (int fm = 0; fm < 4; ++fm)
        av[fm] = *(const bf16x8*)&As[swz64(wr * 64 + fm * 16 + lr, ke)];
#pragma unroll
      for (int fn = 0; fn < 4; ++fn)
        bv[fn] = *(const bf16x8*)&Bs[swz64(wc * 64 + fn * 16 + lr, ke)];
#pragma unroll
      for (int fm = 0; fm < 4; ++fm)
#pragma unroll
        for (int fn = 0; fn < 4; ++fn)
          acc[fm][fn] = __builtin_amdgcn_mfma_f32_16x16x32_bf16(av[fm], bv[fn],
                                                                acc[fm][fn], 0, 0, 0);
    }
  }
  __syncthreads();  // compute reads done; smem becomes epilogue tile
  const int rq = lane >> 4;
  if (!OUTF32) {
    unsigned short* Cs = smem;  // 128 x (stride 136)
#pragma unroll
    for (int fn = 0; fn < 4; ++fn) {
      int col = wc * 64 + fn * 16 + lr;
      float bb = bias[n0 + col];
#pragma unroll
      for (int fm = 0; fm < 4; ++fm) {
        int row = wr * 64 + fm * 16 + rq * 4;
#pragma unroll
        for (int jj = 0; jj < 4; ++jj)
          Cs[(row + jj) * 136 + col] = f2bf(acc[fm][fn][jj] + bb);
      }
    }
    __syncthreads();
    unsigned short* Yb = (unsigned short*)Yv + (size_t)(n0 >> 9) * YHALF;
    const int nc = n0 & 511;
#pragma unroll
    for (int i = 0; i < 8; ++i) {
      int idx = tid + i * 256;     // 0..2047
      int row = idx >> 4, g = idx & 15;
      *(uint4*)(Yb + (size_t)(m0 + row) * 512 + nc + g * 8) =
          *(const uint4*)&Cs[row * 136 + g * 8];
    }
  } else {
    float* Cf = (float*)smem;  // 64 x (stride 132)
    float* Yf = (float*)Yv;
#pragma unroll
    for (int p = 0; p < 2; ++p) {
      if (p) __syncthreads();
      if (wr == p) {
#pragma unroll
        for (int fn = 0; fn < 4; ++fn) {
          int col = wc * 64 + fn * 16 + lr;
          float bb = bias[n0 + col];
#pragma unroll
          for (int fm = 0; fm < 4; ++fm) {
            int lrow = fm * 16 + rq * 4;
#pragma unroll
            for (int jj = 0; jj < 4; ++jj)
              Cf[(lrow + jj) * 132 + col] = acc[fm][fn][jj] + bb;
          }
        }
      }
      __syncthreads();
#pragma unroll
      for (int i = 0; i < 8; ++i) {
        int idx = tid + i * 256;
        int row = idx >> 5, g = idx & 31;
        *(float4*)(Yf + (size_t)(m0 + p * 64 + row) * 512 + n0 + g * 4) =
            *(const float4*)&Cf[row * 132 + g * 4];
      }
    }
  }
}

// ---------------------------------------------------------------------------
// k softmax column stats (unchanged from R6 — passing)
// ---------------------------------------------------------------------------
__global__ __launch_bounds__(256) void kcolstats_part(
    const unsigned short* __restrict__ Kp, float* __restrict__ pmax,
    float* __restrict__ psum) {
  int b = blockIdx.x;
  int chunk = blockIdx.y;
  int gx = threadIdx.x;
  int sy = threadIdx.y;
  const unsigned short* base = Kp + ((size_t)b * L_DIM + chunk * 128) * 512 + gx * 8;
  __shared__ float red[4][512];
  float m[8];
#pragma unroll
  for (int k = 0; k < 8; ++k) m[k] = -3.0e38f;
  for (int s = sy; s < 128; s += 4) {
    uint4 q = *(const uint4*)(base + (size_t)s * 512);
    float v[8];
    unpk8(q, v);
#pragma unroll
    for (int k = 0; k < 8; ++k) m[k] = fmaxf(m[k], v[k]);
  }
  *(float4*)&red[sy][gx * 8] = make_float4(m[0], m[1], m[2], m[3]);
  *(float4*)&red[sy][gx * 8 + 4] = make_float4(m[4], m[5], m[6], m[7]);
  __syncthreads();
#pragma unroll
  for (int k = 0; k < 8; ++k) {
    int f = gx * 8 + k;
    m[k] = fmaxf(fmaxf(red[0][f], red[1][f]), fmaxf(red[2][f], red[3][f]));
  }
  __syncthreads();
  float sum[8];
#pragma unroll
  for (int k = 0; k < 8; ++k) sum[k] = 0.f;
  for (int s = sy; s < 128; s += 4) {
    uint4 q = *(const uint4*)(base + (size_t)s * 512);
    float v[8];
    unpk8(q, v);
#pragma unroll
    for (int k = 0; k < 8; ++k) sum[k] += __expf(v[k] - m[k]);
  }
  *(float4*)&red[sy][gx * 8] = make_float4(sum[0], sum[1], sum[2], sum[3]);
  *(float4*)&red[sy][gx * 8 + 4] = make_float4(sum[4], sum[5], sum[6], sum[7]);
  __syncthreads();
  if (sy == 0) {
#pragma unroll
    for (int k = 0; k < 8; ++k) {
      int f = gx * 8 + k;
      float s = (red[0][f] + red[1][f]) + (red[2][f] + red[3][f]);
      pmax[(size_t)chunk * 4096 + b * E_DIM + f] = m[k];
      psum[(size_t)chunk * 4096 + b * E_DIM + f] = s;
    }
  }
}

__global__ void kcolstats_reduce(const float* __restrict__ pmax,
                                 const float* __restrict__ psum,
                                 float* __restrict__ colmax,
                                 float* __restrict__ colinv) {
  int i = blockIdx.x * 256 + threadIdx.x;
  float M = -3.0e38f, S = 0.f;
#pragma unroll
  for (int c = 0; c < 32; ++c) {
    float m = pmax[(size_t)c * 4096 + i];
    float s = psum[(size_t)c * 4096 + i];
    float nm = fmaxf(M, m);
    S = S * __expf(M - nm) + s * __expf(m - nm);
    M = nm;
  }
  colmax[i] = M;
  colinv[i] = 1.f / S;
}

// ---------------------------------------------------------------------------
// kv partials via MFMA (unchanged from R5 — passing)
// ---------------------------------------------------------------------------
__global__ __launch_bounds__(256) void kv_mfma(
    const unsigned short* __restrict__ Kp, const unsigned short* __restrict__ Vpb,
    const float* __restrict__ colmax, const float* __restrict__ colinv,
    const float* __restrict__ sintab, const float* __restrict__ costab,
    float* __restrict__ kvpart) {
  __shared__ __align__(16) unsigned short kT[64 * 64];
  __shared__ __align__(16) unsigned short vT[128 * 64];
  __shared__ float cmaxs[64], cinvs[64];
  const int tid = threadIdx.x;
  const int chunk = blockIdx.x;
  const int n = blockIdx.y;
  const int b = n >> 3, h = n & 7;
  if (tid < 64) {
    cmaxs[tid] = colmax[b * E_DIM + h * 64 + tid];
    cinvs[tid] = colinv[b * E_DIM + h * 64 + tid];
  }
  const int lane = tid & 63;
  const int w = tid >> 6;
  const int lr = lane & 15;
  const int lk = (lane >> 4) * 8;
  const int sp = tid & 31;
  const int g = tid >> 5;
  f32x4 acc[4][2];
#pragma unroll
  for (int i = 0; i < 4; ++i) {
    acc[i][0] = (f32x4){0.f, 0.f, 0.f, 0.f};
    acc[i][1] = (f32x4){0.f, 0.f, 0.f, 0.f};
  }
  __syncthreads();

  for (int st = 0; st < 8; ++st) {
    int sA = chunk * 512 + st * 64 + 2 * sp;
    const unsigned short* kp = Kp + ((size_t)b * L_DIM + sA) * 512 + h * 64 + g * 8;
    uint4 ka = *(const uint4*)kp;
    uint4 kb = *(const uint4*)(kp + 512);
    int vr = ((sA >> 9) << 12) + ((sA & 511) << 3) + b;
    const unsigned short* vp = Vpb + (size_t)vr * 512 + h * 64 + g * 8;
    uint4 v0 = *(const uint4*)vp;
    uint4 v1 = *(const uint4*)(vp + 8 * 512);
    float kfa[8], kfb[8], vA[8], vB[8];
    unpk8(ka, kfa);
    unpk8(kb, kfb);
    unpk8(v0, vA);
    unpk8(v1, vB);
    float sS = sintab[sA], sC = costab[sA];
    float tS = sintab[sA + 1], tC = costab[sA + 1];
    __syncthreads();
#pragma unroll
    for (int i = 0; i < 8; ++i) {
      int d = g * 8 + i;
      float e0 = __expf(kfa[i] - cmaxs[d]) * cinvs[d];
      float e1 = __expf(kfb[i] - cmaxs[d]) * cinvs[d];
      *(unsigned int*)&kT[swz64(d, 2 * sp)] = pkbf(e0, e1);
    }
#pragma unroll
    for (int i = 0; i < 8; ++i) {
      int m = g * 8 + i;
      *(unsigned int*)&vT[swz64(m, 2 * sp)] = pkbf(vA[i] * sS, vB[i] * tS);
      *(unsigned int*)&vT[swz64(64 + m, 2 * sp)] = pkbf(vA[i] * sC, vB[i] * tC);
    }
    __syncthreads();
#pragma unroll
    for (int kk = 0; kk < 2; ++kk) {
      int ke = kk * 32 + lk;
      bf16x8 av[4], bv[2];
#pragma unroll
      for (int fm = 0; fm < 4; ++fm)
        av[fm] = *(const bf16x8*)&kT[swz64(fm * 16 + lr, ke)];
#pragma unroll
      for (int fn = 0; fn < 2; ++fn)
        bv[fn] = *(const bf16x8*)&vT[swz64(w * 32 + fn * 16 + lr, ke)];
#pragma unroll
      for (int fm = 0; fm < 4; ++fm)
#pragma unroll
        for (int fn = 0; fn < 2; ++fn)
          acc[fm][fn] = __builtin_amdgcn_mfma_f32_16x16x32_bf16(av[fm], bv[fn],
                                                                acc[fm][fn], 0, 0, 0);
    }
  }
  const int rq = lane >> 4;
#pragma unroll
  for (int fn = 0; fn < 2; ++fn) {
    int ncol = w * 32 + fn * 16 + lr;
    int m = ncol & 63;
    int ddbase = (ncol >> 6) * 64;
#pragma unroll
    for (int fm = 0; fm < 4; ++fm) {
#pragma unroll
      for (int jj = 0; jj < 4; ++jj) {
        int dd = ddbase + fm * 16 + rq * 4 + jj;
        kvpart[(((size_t)chunk * 64 + n) * 64 + m) * 128 + dd] = acc[fm][fn][jj];
      }
    }
  }
}

// reduce 8 chunks -> kvT bf16, pre-swizzled [n][m][dd']
__global__ void kv_reduce_swz(const float* __restrict__ part,
                              unsigned short* __restrict__ kvT) {
  int i = blockIdx.x * 256 + threadIdx.x;
  float s = 0.f;
#pragma unroll
  for (int c = 0; c < 8; ++c) s += part[(size_t)c * 524288 + i];
  int dd = i & 127;
  int m = (i >> 7) & 63;
  int nm = i >> 7;
  int gg = dd >> 3;
  int e = ((gg & 8) | ((gg ^ m) & 7)) * 8 + (dd & 7);
  kvT[(size_t)nm * 128 + e] = f2bf(s);
}

// ---------------------------------------------------------------------------
// Fused out pass (unchanged from R6 — passing)
// ---------------------------------------------------------------------------
__global__ __launch_bounds__(256) void out_fused(
    const unsigned short* __restrict__ Qp0, const unsigned short* __restrict__ Qp1,
    const unsigned short* __restrict__ kvT,
    const float* __restrict__ sintab, const float* __restrict__ costab,
    unsigned short* __restrict__ Yb) {
  __shared__ __align__(16) unsigned short q2s[64 * 128];
  __shared__ __align__(16) unsigned short kvs[2][64 * 128];
  const int tid = threadIdx.x;
  const int lc = blockIdx.x;
  const int n = blockIdx.y;
  const int b = n >> 3, h = n & 7;
  const int lane = tid & 63;
  const int w = tid >> 6;
  {
    const uint4* s0 = (const uint4*)(kvT + (size_t)n * 8192);
    const uint4* s1 = (const uint4*)(kvT + 524288 + (size_t)n * 8192);
    uint4* d0 = (uint4*)kvs[0];
    uint4* d1 = (uint4*)kvs[1];
#pragma unroll
    for (int i = 0; i < 4; ++i) {
      d0[tid + i * 256] = s0[tid + i * 256];
      d1[tid + i * 256] = s1[tid + i * 256];
    }
  }
  const int l0 = lc * 64;
  const int wr = w >> 1, wc = w & 1;
  const int lr = lane & 15;
  const int lk = (lane >> 4) * 8;
  const int rq = lane >> 4;
  f32x4 acc[2][2];
  acc[0][0] = acc[0][1] = acc[1][0] = acc[1][1] = (f32x4){0.f, 0.f, 0.f, 0.f};
#pragma unroll
  for (int t = 0; t < 2; ++t) {
    const unsigned short* Qp = t ? Qp1 : Qp0;
    if (t) __syncthreads();
#pragma unroll
    for (int i = 0; i < 2; ++i) {
      int idx = tid + i * 256;
      int row = idx >> 3;
      int g = idx & 7;
      uint4 q = *(const uint4*)(Qp + ((size_t)b * L_DIM + l0 + row) * 512 +
                                h * 64 + g * 8);
      float v[8];
      unpk8(q, v);
      float m8 = fmaxf(fmaxf(fmaxf(v[0], v[1]), fmaxf(v[2], v[3])),
                       fmaxf(fmaxf(v[4], v[5]), fmaxf(v[6], v[7])));
      m8 = fmaxf(m8, __shfl_xor(m8, 1));
      m8 = fmaxf(m8, __shfl_xor(m8, 2));
      m8 = fmaxf(m8, __shfl_xor(m8, 4));
      float e[8], s8;
#pragma unroll
      for (int k = 0; k < 8; ++k) e[k] = __expf(v[k] - m8);
      s8 = ((e[0] + e[1]) + (e[2] + e[3])) + ((e[4] + e[5]) + (e[6] + e[7]));
      s8 += __shfl_xor(s8, 1);
      s8 += __shfl_xor(s8, 2);
      s8 += __shfl_xor(s8, 4);
      float inv = 1.f / s8;
      int gl = l0 + row;
      float sn = sintab[gl] * inv;
      float cs = costab[gl] * inv;
      uint4 os, oc;
      os.x = pkbf(e[0] * sn, e[1] * sn); os.y = pkbf(e[2] * sn, e[3] * sn);
      os.z = pkbf(e[4] * sn, e[5] * sn); os.w = pkbf(e[6] * sn, e[7] * sn);
      oc.x = pkbf(e[0] * cs, e[1] * cs); oc.y = pkbf(e[2] * cs, e[3] * cs);
      oc.z = pkbf(e[4] * cs, e[5] * cs); oc.w = pkbf(e[6] * cs, e[7] * cs);
      *(uint4*)&q2s[swz128(row, g * 8)] = os;
      *(uint4*)&q2s[swz128(row, 64 + g * 8)] = oc;
    }
    __syncthreads();
#pragma unroll
    for (int ks = 0; ks < 4; ++ks) {
      int ke = ks * 32 + lk;
      bf16x8 av[2], bv[2];
#pragma unroll
      for (int fm = 0; fm < 2; ++fm)
        av[fm] = *(const bf16x8*)&q2s[swz128(wr * 32 + fm * 16 + lr, ke)];
#pragma unroll
      for (int fn = 0; fn < 2; ++fn)
        bv[fn] = *(const bf16x8*)&kvs[t][swz128(wc * 32 + fn * 16 + lr, ke)];
#pragma unroll
      for (int fm = 0; fm < 2; ++fm)
#pragma unroll
        for (int fn = 0; fn < 2; ++fn)
          acc[fm][fn] = __builtin_amdgcn_mfma_f32_16x16x32_bf16(av[fm], bv[fn],
                                                                acc[fm][fn], 0, 0, 0);
    }
  }
  __syncthreads();
  unsigned short* Os = q2s;  // 64 x (stride 72)
#pragma unroll
  for (int fn = 0; fn < 2; ++fn) {
    int col = wc * 32 + fn * 16 + lr;
#pragma unroll
    for (int fm = 0; fm < 2; ++fm) {
      int lrow = wr * 32 + fm * 16 + rq * 4;
#pragma unroll
      for (int jj = 0; jj < 4; ++jj)
        Os[(lrow + jj) * 72 + col] = f2bf(acc[fm][fn][jj]);
    }
  }
  __syncthreads();
#pragma unroll
  for (int i = 0; i < 2; ++i) {
    int idx = tid + i * 256;
    int row = idx >> 3, g = idx & 7;
    *(uint4*)(Yb + ((size_t)b * L_DIM + l0 + row) * 512 + h * 64 + g * 8) =
        *(const uint4*)&Os[row * 72 + g * 8];
  }
}

// ---------------------------------------------------------------------------
extern "C" void kernel_launch(void* const* d_in, const int* in_sizes, int n_in,
                              void* d_out, int out_size, void* d_ws, size_t ws_size,
                              hipStream_t stream) {
  const float* query = (const float*)d_in[0];
  const float* key   = (const float*)d_in[1];
  const float* value = (const float*)d_in[2];
  const float* Wq    = (const float*)d_in[3];
  const float* bq    = (const float*)d_in[4];
  const float* Wk    = (const float*)d_in[5];
  const float* bk    = (const float*)d_in[6];
  const float* Wv    = (const float*)d_in[7];
  const float* bv    = (const float*)d_in[8];
  const float* Wout  = (const float*)d_in[9];
  const float* bout  = (const float*)d_in[10];
  float* out = (float*)d_out;
  float* ws = (float*)d_ws;

  // workspace (fp32 slot units)
  const size_t F_PROJ0 = 0;                       // 32768x512 bf16 (t0)
  const size_t F_PROJ1 = F_PROJ0 + 8388608;       // 32768x512 bf16 (t1)
  const size_t F_VPB   = F_PROJ1 + 8388608;       // V proj bf16
  const size_t F_KVP   = F_VPB + 8388608;         // kv partials fp32
  const size_t F_KVT   = F_KVP + 4194304;         // kvT bf16, 2 terms
  const size_t F_XBUF  = F_KVT + 524288;          // bf16 input / attn-out (shared)
  const size_t F_WBF   = F_XBUF + 8388608;        // weights bf16
  const size_t F_CMAX  = F_WBF + 786432;
  const size_t F_CINV  = F_CMAX + 4096;
  const size_t F_SIN   = F_CINV + 4096;
  const size_t F_COS   = F_SIN + 4096;
  const size_t TOTALF  = F_COS + 4096;
  if (ws_size < TOTALF * sizeof(float)) {
    fprintf(stderr, "kernel_launch: ws too small (%zu < %zu)\n", ws_size, TOTALF * 4);
    return;
  }
  unsigned short* proj0 = (unsigned short*)(ws + F_PROJ0);
  unsigned short* vpb   = (unsigned short*)(ws + F_VPB);
  float* kvpart = ws + F_KVP;
  unsigned short* kvT  = (unsigned short*)(ws + F_KVT);
  unsigned short* xbuf = (unsigned short*)(ws + F_XBUF);
  unsigned short* wbf  = (unsigned short*)(ws + F_WBF);
  float* cmax = ws + F_CMAX;
  float* cinv = ws + F_CINV;
  float* sintab = ws + F_SIN;
  float* costab = ws + F_COS;
  float* pmax = kvpart;           // disjoint lifetime aliases
  float* psum = kvpart + 131072;
  const size_t WQ_O = 0, WK_O = 524288, WV_O = 1048576, WOUT_O = 1310720;

  sincos_kernel<<<16, 256, 0, stream>>>(sintab, costab);
  convf2b<<<256, 256, 0, stream>>>(Wq, wbf + WQ_O, 65536);
  convf2b<<<256, 256, 0, stream>>>(Wk, wbf + WK_O, 65536);
  convf2b<<<128, 256, 0, stream>>>(Wv, wbf + WV_O, 32768);
  convf2b<<<128, 256, 0, stream>>>(Wout, wbf + WOUT_O, 32768);

  // V projection: value -> bf16 (xbuf) -> GEMM -> vpb
  convf2b<<<2048, 256, 0, stream>>>(value, xbuf, 2097152);
  gemm_xwt<false, 2><<<1024, 256, 0, stream>>>(xbuf, wbf + WV_O, bv, vpb);

  // K projections, both terms in one N=1024 GEMM (key read once)
  convf2b<<<2048, 256, 0, stream>>>(key, xbuf, 2097152);
  gemm_xwt<false, 3><<<2048, 256, 0, stream>>>(xbuf, wbf + WK_O, bk, proj0);
  for (int t = 0; t < T_DIM; ++t) {
    unsigned short* projt = proj0 + (size_t)t * YHALF;
    kcolstats_part<<<dim3(8, 32), dim3(64, 4), 0, stream>>>(projt, pmax, psum);
    kcolstats_reduce<<<16, 256, 0, stream>>>(pmax, psum, cmax, cinv);
    kv_mfma<<<dim3(8, 64), 256, 0, stream>>>(projt, vpb, cmax, cinv,
                                             sintab, costab, kvpart);
    kv_reduce_swz<<<2048, 256, 0, stream>>>(kvpart, kvT + (size_t)t * 524288);
  }

  // Q projections, both terms in one N=1024 GEMM (query read once)
  convf2b<<<2048, 256, 0, stream>>>(query, xbuf, 2097152);
  gemm_xwt<false, 3><<<2048, 256, 0, stream>>>(xbuf, wbf + WQ_O, bq, proj0);
  // fused output accumulation -> xbuf (overwrites query-bf16; Q GEMM is done)
  out_fused<<<dim3(64, 64), 256, 0, stream>>>(proj0, proj0 + YHALF, kvT,
                                              sintab, costab, xbuf);
  // final projection: bf16 A, fp32 out
  gemm_xwt<true, 2><<<1024, 256, 0, stream>>>(xbuf, wbf + WOUT_O, bout, out);
}

// Round 8
// 325.787 us; speedup vs baseline: 2.7032x; 1.1190x over previous
//
#include <hip/hip_runtime.h>
#include <cstdio>

#define E_DIM 512
#define L_DIM 4096
#define B_DIM 8
#define H_DIM 8
#define T_DIM 2
#define M_ROWS 32768

typedef __attribute__((ext_vector_type(8))) __bf16 bf16x8;
typedef __attribute__((ext_vector_type(4))) float f32x4;

static __device__ __forceinline__ unsigned short f2bf(float f) {
  unsigned int u = __float_as_uint(f);
  return (unsigned short)((u + 0x7FFFu + ((u >> 16) & 1u)) >> 16);
}
static __device__ __forceinline__ unsigned int pkbf(float lo, float hi) {
  return (unsigned int)f2bf(lo) | ((unsigned int)f2bf(hi) << 16);
}
static __device__ __forceinline__ float bf2f(unsigned short u) {
  return __uint_as_float((unsigned int)u << 16);
}
static __device__ __forceinline__ void unpk8(uint4 u, float* f) {
  f[0] = bf2f((unsigned short)u.x); f[1] = bf2f((unsigned short)(u.x >> 16));
  f[2] = bf2f((unsigned short)u.y); f[3] = bf2f((unsigned short)(u.y >> 16));
  f[4] = bf2f((unsigned short)u.z); f[5] = bf2f((unsigned short)(u.z >> 16));
  f[6] = bf2f((unsigned short)u.w); f[7] = bf2f((unsigned short)(u.w >> 16));
}
// XOR swizzle at 8-elem (16B) granules
static __device__ __forceinline__ int swz64(int row, int e) {
  return row * 64 + ((((e >> 3) ^ row) & 7) << 3) + (e & 7);
}
static __device__ __forceinline__ int swz128(int row, int e) {
  return row * 128 + ((((e >> 3) ^ row) & 7) << 3) + ((e >> 3) & 8) * 8 + (e & 7);
}
// async global->LDS, 16B per lane; LDS dest = wave-uniform base + lane*16
static __device__ __forceinline__ void gl_lds16(const unsigned short* g,
                                                unsigned short* l) {
  __builtin_amdgcn_global_load_lds(
      (const __attribute__((address_space(1))) unsigned int*)g,
      (__attribute__((address_space(3))) unsigned int*)l, 16, 0, 0);
}

// ---------------------------------------------------------------------------
__global__ void sincos_kernel(float* __restrict__ sintab, float* __restrict__ costab) {
  int i = blockIdx.x * blockDim.x + threadIdx.x;
  if (i < L_DIM) {
    float idx = 1.57079632679489662f * (float)(i + 1) / (float)L_DIM;
    sintab[i] = sinf(idx);
    costab[i] = cosf(idx);
  }
}

__global__ void convf2b(const float* __restrict__ src, unsigned short* __restrict__ dst,
                        int n8) {
  for (int i = blockIdx.x * blockDim.x + threadIdx.x; i < n8; i += gridDim.x * blockDim.x) {
    float4 a = *(const float4*)(src + (size_t)i * 8);
    float4 b = *(const float4*)(src + (size_t)i * 8 + 4);
    uint4 o;
    o.x = pkbf(a.x, a.y); o.y = pkbf(a.z, a.w);
    o.z = pkbf(b.x, b.y); o.w = pkbf(b.z, b.w);
    *(uint4*)(dst + (size_t)i * 8) = o;
  }
}

// ---------------------------------------------------------------------------
// Y[M][N] = X[M][512] @ W[N][512]^T + bias[N]; N = 512<<(NBL2-2).
// bf16 X,W. Double-buffered LDS: issue next K-tile's global_load_lds before
// computing current tile; one barrier per K-step (T3 minimal 2-phase).
// STATS: fused per-128-row-tile column softmax partials (max/sum over rows,
// fp32 acc + bias) -> pmax/psum[mtile][N].
// ---------------------------------------------------------------------------
#define YHALF 16777216
template <bool OUTF32, bool STATS, int NBL2>
__global__ __launch_bounds__(256) void gemm_xwt(
    const unsigned short* __restrict__ X, const unsigned short* __restrict__ W,
    const float* __restrict__ bias, void* __restrict__ Yv,
    float* __restrict__ pmax, float* __restrict__ psum) {
  __shared__ __align__(16) unsigned short smem[32768];  // 2 x (As 8192 + Bs 8192)
  const int tid = threadIdx.x;
  const int id = blockIdx.x;
  const int j = id >> 3;
  const int mb = (id & 7) * 32 + (j >> NBL2);
  const int nb = j & ((1 << NBL2) - 1);
  const int m0 = mb * 128, n0 = nb * 128;
  const int lane = tid & 63;
  const int w = tid >> 6;
  const int wr = w >> 1, wc = w & 1;
  const int lr = lane & 15;
  const int lk = (lane >> 4) * 8;
  const int rq = lane >> 4;
  // staging geometry: wave w covers rows w*32..+31, 8 rows per instruction
  const int srow = lane >> 3;            // 0..7
  const int gsrc8 = ((lane & 7) ^ srow) * 8;  // inverse-swizzled source granule
  f32x4 acc[4][4];
#pragma unroll
  for (int i = 0; i < 4; ++i)
#pragma unroll
    for (int jj = 0; jj < 4; ++jj) acc[i][jj] = (f32x4){0.f, 0.f, 0.f, 0.f};

  // prologue: stage tile 0 into buffer 0
#pragma unroll
  for (int i = 0; i < 4; ++i) {
    int rb = w * 32 + i * 8;
    gl_lds16(X + (size_t)(m0 + rb + srow) * 512 + gsrc8, &smem[rb * 64]);
    gl_lds16(W + (size_t)(n0 + rb + srow) * 512 + gsrc8, &smem[8192 + rb * 64]);
  }
  __syncthreads();  // vmcnt(0) drain -> tile 0 ready

#pragma unroll
  for (int step = 0; step < 8; ++step) {
    const int cur = step & 1;
    if (step < 7) {
      // issue next tile's loads into the other buffer (in flight during MFMA)
      unsigned short* Ab = smem + (cur ^ 1) * 16384;
      const int kn = (step + 1) * 64;
#pragma unroll
      for (int i = 0; i < 4; ++i) {
        int rb = w * 32 + i * 8;
        gl_lds16(X + (size_t)(m0 + rb + srow) * 512 + kn + gsrc8, &Ab[rb * 64]);
        gl_lds16(W + (size_t)(n0 + rb + srow) * 512 + kn + gsrc8,
                 &Ab[8192 + rb * 64]);
      }
    }
    const unsigned short* As = smem + cur * 16384;
    const unsigned short* Bs = As + 8192;
#pragma unroll
    for (int kk = 0; kk < 2; ++kk) {
      bf16x8 av[4], bv[4];
      int ke = kk * 32 + lk;
#pragma unroll
      for (int fm = 0; fm < 4; ++fm)
        av[fm] = *(const bf16x8*)&As[swz64(wr * 64 + fm * 16 + lr, ke)];
#pragma unroll
      for (int fn = 0; fn < 4; ++fn)
        bv[fn] = *(const bf16x8*)&Bs[swz64(wc * 64 + fn * 16 + lr, ke)];
#pragma unroll
      for (int fm = 0; fm < 4; ++fm)
#pragma unroll
        for (int fn = 0; fn < 4; ++fn)
          acc[fm][fn] = __builtin_amdgcn_mfma_f32_16x16x32_bf16(av[fm], bv[fn],
                                                                acc[fm][fn], 0, 0, 0);
    }
    __syncthreads();  // drains next-tile vmcnt + this tile's lgkm reads
  }

  // ---- fused column-softmax stats (over the tile's 128 rows) ----
  if (STATS) {
    float* sf = (float*)smem;  // [2][128] max @0, [2][128] sum @256
#pragma unroll
    for (int fn = 0; fn < 4; ++fn) {
      float M = -3.0e38f;
#pragma unroll
      for (int fm = 0; fm < 4; ++fm)
#pragma unroll
        for (int jj = 0; jj < 4; ++jj) M = fmaxf(M, acc[fm][fn][jj]);
      // wave-level column max over 64 rows (combine rq groups)
      M = fmaxf(M, __shfl_xor(M, 16));
      M = fmaxf(M, __shfl_xor(M, 32));
      float S = 0.f;
#pragma unroll
      for (int fm = 0; fm < 4; ++fm)
#pragma unroll
        for (int jj = 0; jj < 4; ++jj) S += __expf(acc[fm][fn][jj] - M);
      S += __shfl_xor(S, 16);
      S += __shfl_xor(S, 32);
      if (rq == 0) {
        int col = wc * 64 + fn * 16 + lr;
        sf[wr * 128 + col] = M;
        sf[256 + wr * 128 + col] = S;
      }
    }
    __syncthreads();
    if (tid < 128) {
      float M0 = sf[tid], M1 = sf[128 + tid];
      float S0 = sf[256 + tid], S1 = sf[384 + tid];
      float nm = fmaxf(M0, M1);
      float S = S0 * __expf(M0 - nm) + S1 * __expf(M1 - nm);
      int gc = n0 + tid;
      size_t mtile = (size_t)(m0 >> 7);
      pmax[mtile * (128 << NBL2) + gc] = nm + bias[gc];  // bias shifts max only
      psum[mtile * (128 << NBL2) + gc] = S;
    }
    __syncthreads();
  }

  // ---- epilogue: LDS-staged vectorized store ----
  if (!OUTF32) {
    unsigned short* Cs = smem;  // 128 x (stride 136)
#pragma unroll
    for (int fn = 0; fn < 4; ++fn) {
      int col = wc * 64 + fn * 16 + lr;
      float bb = bias[n0 + col];
#pragma unroll
      for (int fm = 0; fm < 4; ++fm) {
        int row = wr * 64 + fm * 16 + rq * 4;
#pragma unroll
        for (int jj = 0; jj < 4; ++jj)
          Cs[(row + jj) * 136 + col] = f2bf(acc[fm][fn][jj] + bb);
      }
    }
    __syncthreads();
    unsigned short* Yb = (unsigned short*)Yv + (size_t)(n0 >> 9) * YHALF;
    const int nc = n0 & 511;
#pragma unroll
    for (int i = 0; i < 8; ++i) {
      int idx = tid + i * 256;     // 0..2047
      int row = idx >> 4, g = idx & 15;
      *(uint4*)(Yb + (size_t)(m0 + row) * 512 + nc + g * 8) =
          *(const uint4*)&Cs[row * 136 + g * 8];
    }
  } else {
    float* Cf = (float*)smem;  // 64 x (stride 132)
    float* Yf = (float*)Yv;
#pragma unroll
    for (int p = 0; p < 2; ++p) {
      if (p) __syncthreads();
      if (wr == p) {
#pragma unroll
        for (int fn = 0; fn < 4; ++fn) {
          int col = wc * 64 + fn * 16 + lr;
          float bb = bias[n0 + col];
#pragma unroll
          for (int fm = 0; fm < 4; ++fm) {
            int lrow = fm * 16 + rq * 4;
#pragma unroll
            for (int jj = 0; jj < 4; ++jj)
              Cf[(lrow + jj) * 132 + col] = acc[fm][fn][jj] + bb;
          }
        }
      }
      __syncthreads();
#pragma unroll
      for (int i = 0; i < 8; ++i) {
        int idx = tid + i * 256;
        int row = idx >> 5, g = idx & 31;
        *(float4*)(Yf + (size_t)(m0 + p * 64 + row) * 512 + n0 + g * 4) =
            *(const float4*)&Cf[row * 132 + g * 4];
      }
    }
  }
}

// ---------------------------------------------------------------------------
// reduce per-mtile stats over the 32 mtiles of each b; coloff selects term
// ---------------------------------------------------------------------------
__global__ void kcolstats_reduce(const float* __restrict__ pmax,
                                 const float* __restrict__ psum,
                                 float* __restrict__ colmax,
                                 float* __restrict__ colinv, int coloff) {
  int i = blockIdx.x * 256 + threadIdx.x;  // b*512+f, 0..4095
  int b = i >> 9, f = i & 511;
  float M = -3.0e38f, S = 0.f;
#pragma unroll
  for (int c = 0; c < 32; ++c) {
    size_t mt = (size_t)(b * 32 + c);
    float m = pmax[mt * 1024 + coloff + f];
    float s = psum[mt * 1024 + coloff + f];
    float nm = fmaxf(M, m);
    S = S * __expf(M - nm) + s * __expf(m - nm);
    M = nm;
  }
  colmax[i] = M;
  colinv[i] = 1.f / S;
}

// ---------------------------------------------------------------------------
// kv partials via MFMA (unchanged — passing)
// ---------------------------------------------------------------------------
__global__ __launch_bounds__(256) void kv_mfma(
    const unsigned short* __restrict__ Kp, const unsigned short* __restrict__ Vpb,
    const float* __restrict__ colmax, const float* __restrict__ colinv,
    const float* __restrict__ sintab, const float* __restrict__ costab,
    float* __restrict__ kvpart) {
  __shared__ __align__(16) unsigned short kT[64 * 64];
  __shared__ __align__(16) unsigned short vT[128 * 64];
  __shared__ float cmaxs[64], cinvs[64];
  const int tid = threadIdx.x;
  const int chunk = blockIdx.x;
  const int n = blockIdx.y;
  const int b = n >> 3, h = n & 7;
  if (tid < 64) {
    cmaxs[tid] = colmax[b * E_DIM + h * 64 + tid];
    cinvs[tid] = colinv[b * E_DIM + h * 64 + tid];
  }
  const int lane = tid & 63;
  const int w = tid >> 6;
  const int lr = lane & 15;
  const int lk = (lane >> 4) * 8;
  const int sp = tid & 31;
  const int g = tid >> 5;
  f32x4 acc[4][2];
#pragma unroll
  for (int i = 0; i < 4; ++i) {
    acc[i][0] = (f32x4){0.f, 0.f, 0.f, 0.f};
    acc[i][1] = (f32x4){0.f, 0.f, 0.f, 0.f};
  }
  __syncthreads();

  for (int st = 0; st < 8; ++st) {
    int sA = chunk * 512 + st * 64 + 2 * sp;
    const unsigned short* kp = Kp + ((size_t)b * L_DIM + sA) * 512 + h * 64 + g * 8;
    uint4 ka = *(const uint4*)kp;
    uint4 kb = *(const uint4*)(kp + 512);
    int vr = ((sA >> 9) << 12) + ((sA & 511) << 3) + b;
    const unsigned short* vp = Vpb + (size_t)vr * 512 + h * 64 + g * 8;
    uint4 v0 = *(const uint4*)vp;
    uint4 v1 = *(const uint4*)(vp + 8 * 512);
    float kfa[8], kfb[8], vA[8], vB[8];
    unpk8(ka, kfa);
    unpk8(kb, kfb);
    unpk8(v0, vA);
    unpk8(v1, vB);
    float sS = sintab[sA], sC = costab[sA];
    float tS = sintab[sA + 1], tC = costab[sA + 1];
    __syncthreads();
#pragma unroll
    for (int i = 0; i < 8; ++i) {
      int d = g * 8 + i;
      float e0 = __expf(kfa[i] - cmaxs[d]) * cinvs[d];
      float e1 = __expf(kfb[i] - cmaxs[d]) * cinvs[d];
      *(unsigned int*)&kT[swz64(d, 2 * sp)] = pkbf(e0, e1);
    }
#pragma unroll
    for (int i = 0; i < 8; ++i) {
      int m = g * 8 + i;
      *(unsigned int*)&vT[swz64(m, 2 * sp)] = pkbf(vA[i] * sS, vB[i] * tS);
      *(unsigned int*)&vT[swz64(64 + m, 2 * sp)] = pkbf(vA[i] * sC, vB[i] * tC);
    }
    __syncthreads();
#pragma unroll
    for (int kk = 0; kk < 2; ++kk) {
      int ke = kk * 32 + lk;
      bf16x8 av[4], bv[2];
#pragma unroll
      for (int fm = 0; fm < 4; ++fm)
        av[fm] = *(const bf16x8*)&kT[swz64(fm * 16 + lr, ke)];
#pragma unroll
      for (int fn = 0; fn < 2; ++fn)
        bv[fn] = *(const bf16x8*)&vT[swz64(w * 32 + fn * 16 + lr, ke)];
#pragma unroll
      for (int fm = 0; fm < 4; ++fm)
#pragma unroll
        for (int fn = 0; fn < 2; ++fn)
          acc[fm][fn] = __builtin_amdgcn_mfma_f32_16x16x32_bf16(av[fm], bv[fn],
                                                                acc[fm][fn], 0, 0, 0);
    }
  }
  const int rq = lane >> 4;
#pragma unroll
  for (int fn = 0; fn < 2; ++fn) {
    int ncol = w * 32 + fn * 16 + lr;
    int m = ncol & 63;
    int ddbase = (ncol >> 6) * 64;
#pragma unroll
    for (int fm = 0; fm < 4; ++fm) {
#pragma unroll
      for (int jj = 0; jj < 4; ++jj) {
        int dd = ddbase + fm * 16 + rq * 4 + jj;
        kvpart[(((size_t)chunk * 64 + n) * 64 + m) * 128 + dd] = acc[fm][fn][jj];
      }
    }
  }
}

// reduce 8 chunks -> kvT bf16, pre-swizzled [n][m][dd']
__global__ void kv_reduce_swz(const float* __restrict__ part,
                              unsigned short* __restrict__ kvT) {
  int i = blockIdx.x * 256 + threadIdx.x;
  float s = 0.f;
#pragma unroll
  for (int c = 0; c < 8; ++c) s += part[(size_t)c * 524288 + i];
  int dd = i & 127;
  int m = (i >> 7) & 63;
  int nm = i >> 7;
  int gg = dd >> 3;
  int e = ((gg & 8) | ((gg ^ m) & 7)) * 8 + (dd & 7);
  kvT[(size_t)nm * 128 + e] = f2bf(s);
}

// ---------------------------------------------------------------------------
// Fused out pass (unchanged — passing)
// ---------------------------------------------------------------------------
__global__ __launch_bounds__(256) void out_fused(
    const unsigned short* __restrict__ Qp0, const unsigned short* __restrict__ Qp1,
    const unsigned short* __restrict__ kvT,
    const float* __restrict__ sintab, const float* __restrict__ costab,
    unsigned short* __restrict__ Yb) {
  __shared__ __align__(16) unsigned short q2s[64 * 128];
  __shared__ __align__(16) unsigned short kvs[2][64 * 128];
  const int tid = threadIdx.x;
  const int lc = blockIdx.x;
  const int n = blockIdx.y;
  const int b = n >> 3, h = n & 7;
  const int lane = tid & 63;
  const int w = tid >> 6;
  {
    const uint4* s0 = (const uint4*)(kvT + (size_t)n * 8192);
    const uint4* s1 = (const uint4*)(kvT + 524288 + (size_t)n * 8192);
    uint4* d0 = (uint4*)kvs[0];
    uint4* d1 = (uint4*)kvs[1];
#pragma unroll
    for (int i = 0; i < 4; ++i) {
      d0[tid + i * 256] = s0[tid + i * 256];
      d1[tid + i * 256] = s1[tid + i * 256];
    }
  }
  const int l0 = lc * 64;
  const int wr = w >> 1, wc = w & 1;
  const int lr = lane & 15;
  const int lk = (lane >> 4) * 8;
  const int rq = lane >> 4;
  f32x4 acc[2][2];
  acc[0][0] = acc[0][1] = acc[1][0] = acc[1][1] = (f32x4){0.f, 0.f, 0.f, 0.f};
#pragma unroll
  for (int t = 0; t < 2; ++t) {
    const unsigned short* Qp = t ? Qp1 : Qp0;
    if (t) __syncthreads();
#pragma unroll
    for (int i = 0; i < 2; ++i) {
      int idx = tid + i * 256;
      int row = idx >> 3;
      int g = idx & 7;
      uint4 q = *(const uint4*)(Qp + ((size_t)b * L_DIM + l0 + row) * 512 +
                                h * 64 + g * 8);
      float v[8];
      unpk8(q, v);
      float m8 = fmaxf(fmaxf(fmaxf(v[0], v[1]), fmaxf(v[2], v[3])),
                       fmaxf(fmaxf(v[4], v[5]), fmaxf(v[6], v[7])));
      m8 = fmaxf(m8, __shfl_xor(m8, 1));
      m8 = fmaxf(m8, __shfl_xor(m8, 2));
      m8 = fmaxf(m8, __shfl_xor(m8, 4));
      float e[8], s8;
#pragma unroll
      for (int k = 0; k < 8; ++k) e[k] = __expf(v[k] - m8);
      s8 = ((e[0] + e[1]) + (e[2] + e[3])) + ((e[4] + e[5]) + (e[6] + e[7]));
      s8 += __shfl_xor(s8, 1);
      s8 += __shfl_xor(s8, 2);
      s8 += __shfl_xor(s8, 4);
      float inv = 1.f / s8;
      int gl = l0 + row;
      float sn = sintab[gl] * inv;
      float cs = costab[gl] * inv;
      uint4 os, oc;
      os.x = pkbf(e[0] * sn, e[1] * sn); os.y = pkbf(e[2] * sn, e[3] * sn);
      os.z = pkbf(e[4] * sn, e[5] * sn); os.w = pkbf(e[6] * sn, e[7] * sn);
      oc.x = pkbf(e[0] * cs, e[1] * cs); oc.y = pkbf(e[2] * cs, e[3] * cs);
      oc.z = pkbf(e[4] * cs, e[5] * cs); oc.w = pkbf(e[6] * cs, e[7] * cs);
      *(uint4*)&q2s[swz128(row, g * 8)] = os;
      *(uint4*)&q2s[swz128(row, 64 + g * 8)] = oc;
    }
    __syncthreads();
#pragma unroll
    for (int ks = 0; ks < 4; ++ks) {
      int ke = ks * 32 + lk;
      bf16x8 av[2], bv[2];
#pragma unroll
      for (int fm = 0; fm < 2; ++fm)
        av[fm] = *(const bf16x8*)&q2s[swz128(wr * 32 + fm * 16 + lr, ke)];
#pragma unroll
      for (int fn = 0; fn < 2; ++fn)
        bv[fn] = *(const bf16x8*)&kvs[t][swz128(wc * 32 + fn * 16 + lr, ke)];
#pragma unroll
      for (int fm = 0; fm < 2; ++fm)
#pragma unroll
        for (int fn = 0; fn < 2; ++fn)
          acc[fm][fn] = __builtin_amdgcn_mfma_f32_16x16x32_bf16(av[fm], bv[fn],
                                                                acc[fm][fn], 0, 0, 0);
    }
  }
  __syncthreads();
  unsigned short* Os = q2s;  // 64 x (stride 72)
#pragma unroll
  for (int fn = 0; fn < 2; ++fn) {
    int col = wc * 32 + fn * 16 + lr;
#pragma unroll
    for (int fm = 0; fm < 2; ++fm) {
      int lrow = wr * 32 + fm * 16 + rq * 4;
#pragma unroll
      for (int jj = 0; jj < 4; ++jj)
        Os[(lrow + jj) * 72 + col] = f2bf(acc[fm][fn][jj]);
    }
  }
  __syncthreads();
#pragma unroll
  for (int i = 0; i < 2; ++i) {
    int idx = tid + i * 256;
    int row = idx >> 3, g = idx & 7;
    *(uint4*)(Yb + ((size_t)b * L_DIM + l0 + row) * 512 + h * 64 + g * 8) =
        *(const uint4*)&Os[row * 72 + g * 8];
  }
}

// ---------------------------------------------------------------------------
extern "C" void kernel_launch(void* const* d_in, const int* in_sizes, int n_in,
                              void* d_out, int out_size, void* d_ws, size_t ws_size,
                              hipStream_t stream) {
  const float* query = (const float*)d_in[0];
  const float* key   = (const float*)d_in[1];
  const float* value = (const float*)d_in[2];
  const float* Wq    = (const float*)d_in[3];
  const float* bq    = (const float*)d_in[4];
  const float* Wk    = (const float*)d_in[5];
  const float* bk    = (const float*)d_in[6];
  const float* Wv    = (const float*)d_in[7];
  const float* bv    = (const float*)d_in[8];
  const float* Wout  = (const float*)d_in[9];
  const float* bout  = (const float*)d_in[10];
  float* out = (float*)d_out;
  float* ws = (float*)d_ws;

  // workspace (fp32 slot units)
  const size_t F_PROJ0 = 0;                       // 32768x512 bf16 (t0)
  const size_t F_PROJ1 = F_PROJ0 + 8388608;       // 32768x512 bf16 (t1)
  const size_t F_VPB   = F_PROJ1 + 8388608;       // V proj bf16
  const size_t F_KVP   = F_VPB + 8388608;         // kv partials fp32
  const size_t F_KVT   = F_KVP + 4194304;         // kvT bf16, 2 terms
  const size_t F_XBUF  = F_KVT + 524288;          // bf16 input / attn-out (shared)
  const size_t F_WBF   = F_XBUF + 8388608;        // weights bf16
  const size_t F_CMAX  = F_WBF + 786432;          // 2 terms x 4096
  const size_t F_CINV  = F_CMAX + 8192;
  const size_t F_SIN   = F_CINV + 8192;
  const size_t F_COS   = F_SIN + 4096;
  const size_t TOTALF  = F_COS + 4096;
  if (ws_size < TOTALF * sizeof(float)) {
    fprintf(stderr, "kernel_launch: ws too small (%zu < %zu)\n", ws_size, TOTALF * 4);
    return;
  }
  unsigned short* proj0 = (unsigned short*)(ws + F_PROJ0);
  unsigned short* vpb   = (unsigned short*)(ws + F_VPB);
  float* kvpart = ws + F_KVP;
  unsigned short* kvT  = (unsigned short*)(ws + F_KVT);
  unsigned short* xbuf = (unsigned short*)(ws + F_XBUF);
  unsigned short* wbf  = (unsigned short*)(ws + F_WBF);
  float* cmax = ws + F_CMAX;
  float* cinv = ws + F_CINV;
  float* sintab = ws + F_SIN;
  float* costab = ws + F_COS;
  // stats partials alias kvpart: [256 mtiles][1024] each; consumed by both
  // kcolstats_reduce launches BEFORE any kv_mfma writes kvpart.
  float* pmax = kvpart;
  float* psum = kvpart + 262144;
  const size_t WQ_O = 0, WK_O = 524288, WV_O = 1048576, WOUT_O = 1310720;

  sincos_kernel<<<16, 256, 0, stream>>>(sintab, costab);
  convf2b<<<256, 256, 0, stream>>>(Wq, wbf + WQ_O, 65536);
  convf2b<<<256, 256, 0, stream>>>(Wk, wbf + WK_O, 65536);
  convf2b<<<128, 256, 0, stream>>>(Wv, wbf + WV_O, 32768);
  convf2b<<<128, 256, 0, stream>>>(Wout, wbf + WOUT_O, 32768);

  // V projection: value -> bf16 (xbuf) -> GEMM -> vpb
  convf2b<<<2048, 256, 0, stream>>>(value, xbuf, 2097152);
  gemm_xwt<false, false, 2><<<1024, 256, 0, stream>>>(xbuf, wbf + WV_O, bv, vpb,
                                                      nullptr, nullptr);

  // K projections (both terms, N=1024) with fused column-softmax stats
  convf2b<<<2048, 256, 0, stream>>>(key, xbuf, 2097152);
  gemm_xwt<false, true, 3><<<2048, 256, 0, stream>>>(xbuf, wbf + WK_O, bk, proj0,
                                                     pmax, psum);
  kcolstats_reduce<<<16, 256, 0, stream>>>(pmax, psum, cmax, cinv, 0);
  kcolstats_reduce<<<16, 256, 0, stream>>>(pmax, psum, cmax + 4096, cinv + 4096, 512);
  for (int t = 0; t < T_DIM; ++t) {
    unsigned short* projt = proj0 + (size_t)t * YHALF;
    kv_mfma<<<dim3(8, 64), 256, 0, stream>>>(projt, vpb, cmax + t * 4096,
                                             cinv + t * 4096, sintab, costab,
                                             kvpart);
    kv_reduce_swz<<<2048, 256, 0, stream>>>(kvpart, kvT + (size_t)t * 524288);
  }

  // Q projections (both terms, N=1024)
  convf2b<<<2048, 256, 0, stream>>>(query, xbuf, 2097152);
  gemm_xwt<false, false, 3><<<2048, 256, 0, stream>>>(xbuf, wbf + WQ_O, bq, proj0,
                                                      nullptr, nullptr);
  // fused output accumulation -> xbuf (overwrites query-bf16; Q GEMM is done)
  out_fused<<<dim3(64, 64), 256, 0, stream>>>(proj0, proj0 + YHALF, kvT,
                                              sintab, costab, xbuf);
  // final projection: bf16 A, fp32 out
  gemm_xwt<true, false, 2><<<1024, 256, 0, stream>>>(xbuf, wbf + WOUT_O, bout, out,
                                                     nullptr, nullptr);
}